// Round 1
// baseline (746.012 us; speedup 1.0000x reference)
//
#include <hip/hip_runtime.h>
#include <math.h>

#define N_AGENT 60000
#define N_MAP   40000
#define N_NODES 100000
#define NE      3200000
#define HID     32
#define PERIODS 30

#define NBUCK     235        // agent-dst buckets only: ceil(60160/256)
#define AGENT_LIM (NBUCK*256) // 60160 — dst >= this is pure-map, dropped
#define CAP       10240      // per-bucket capacity (mean 8192, +22 sigma)
#define TILE      4096       // edges per partition block
#define PTHREADS  512
#define SPLIT     3          // edge-range slices per bucket in k_agg

// ---------------- kernel 0: fold weights, softmax sum, cursor init ----------------
__global__ void k_precompute(const float* Wz_c, const float* bz_c,
                             const float* Wh_c, const float* bh_c,
                             const float* Wz_l, const float* bz_l,
                             const float* Wh_l, const float* bh_l,
                             const float* attn,
                             float* Mz, float* Mh, float* bz_eff, float* bh_eff,
                             float* s_out, int* cursor) {
    int t = threadIdx.x;            // blockDim = 1024
    int k = t >> 5, c = t & 31;
    float mz = 0.f, mh = 0.f;
    for (int j = 0; j < HID; ++j) {
        mz += Wz_c[k * HID + j] * Wz_l[j * HID + c];   // Wz_l rows 0..31 (zeros half dead)
        mh += Wh_c[k * HID + j] * Wh_l[j * HID + c];
    }
    Mz[t] = mz; Mh[t] = mh;
    if (t < NBUCK) cursor[t] = t * CAP;
    if (t < HID) {
        float bz = bz_l[t], bh = bh_l[t];
        for (int j = 0; j < HID; ++j) {
            bz += bz_c[j] * Wz_l[j * HID + t];
            bh += bh_c[j] * Wh_l[j * HID + t];
        }
        bz_eff[t] = bz; bh_eff[t] = bh;
    }
    if (t == 0) {
        float m = -1e30f;
        for (int i = 0; i < PERIODS; ++i) m = fmaxf(m, attn[i]);
        float S = 0.f;
        for (int i = 0; i < PERIODS; ++i) S += expf(attn[i] - m);
        float s = 0.f;
        for (int i = 0; i < PERIODS; ++i) s += expf(attn[i] - m) / S;
        *s_out = s;
    }
}

// ---------------- kernel 1: in-degree histogram (global atomics) ----------------
__global__ __launch_bounds__(256) void k_deg(const int* __restrict__ dst,
                                             int* __restrict__ deg) {
    int t = blockIdx.x * blockDim.x + threadIdx.x;
    int stride = gridDim.x * blockDim.x;
    const int4* d4 = (const int4*)dst;
    for (int e = t; e < NE / 4; e += stride) {
        int4 d = d4[e];
        atomicAdd(&deg[d.x], 1);
        atomicAdd(&deg[d.y], 1);
        atomicAdd(&deg[d.z], 1);
        atomicAdd(&deg[d.w], 1);
    }
}

// ---------------- kernel 2: node encoders, pre-scaled by dinv[node] ----------------
__global__ void k_encode(const float* __restrict__ agent_x, const float* __restrict__ map_x,
                         const float* __restrict__ W_agent, const float* __restrict__ b_agent,
                         const float* __restrict__ W_map, const float* __restrict__ b_map,
                         const int* __restrict__ deg,
                         float* __restrict__ y) {
    int t = blockIdx.x * blockDim.x + threadIdx.x;
    if (t >= N_NODES * HID) return;
    int i = t >> 5, c = t & 31;
    float acc;
    if (i < N_AGENT) {
        const float* row = agent_x + (size_t)i * 9;
        acc = b_agent[c];
#pragma unroll
        for (int k = 0; k < 9; ++k) acc += row[k] * W_agent[k * HID + c];
    } else {
        const float* row = map_x + (size_t)(i - N_AGENT) * 6;
        acc = b_map[c];
#pragma unroll
        for (int k = 0; k < 6; ++k) acc += row[k] * W_map[k * HID + c];
    }
    float di = rsqrtf((float)deg[i] + 1.0f);
    y[t] = acc * di;                 // fold dinv[src] into the node feature
}

// ---------------- kernel 3: LDS-staged partition (agent-dst edges only) ----------------
// pack = src | (dst_low << 17); bucket = dst >> 8; edges with dst >= AGENT_LIM dropped
__global__ __launch_bounds__(PTHREADS) void k_partition(
        const int* __restrict__ src, const int* __restrict__ dst,
        int* __restrict__ cursor, int* __restrict__ ebuf) {
    __shared__ int sCnt[NBUCK + 1];
    __shared__ int sBase[NBUCK + 1];
    __shared__ int sGbase[NBUCK];
    __shared__ int sScan[PTHREADS];
    __shared__ int sReorder[TILE];
    int t = threadIdx.x;
    int tileBase = blockIdx.x * TILE;

    if (t < NBUCK) sCnt[t] = 0;
    __syncthreads();

    int pb[8]; int pp[8];
#pragma unroll
    for (int k = 0; k < 8; ++k) {
        int e = tileBase + t + k * PTHREADS;
        pb[k] = -1;
        if (e < NE) {
            int s = src[e], d = dst[e];
            if (d < AGENT_LIM) {
                pb[k] = d >> 8;
                pp[k] = s | ((d & 255) << 17);
                atomicAdd(&sCnt[pb[k]], 1);
            }
        }
    }
    __syncthreads();

    // inclusive scan of sCnt via sScan (Hillis-Steele over 512 threads)
    int v = (t < NBUCK) ? sCnt[t] : 0;
    sScan[t] = v;
    __syncthreads();
    for (int s = 1; s < PTHREADS; s <<= 1) {
        int a = (t >= s) ? sScan[t - s] : 0;
        __syncthreads();
        sScan[t] += a;
        __syncthreads();
    }
    if (t <= NBUCK) sBase[t] = sScan[t] - v;   // exclusive; sBase[NBUCK] = kept total
    __syncthreads();
    // reserve global space, reset counters for rank pass
    if (t < NBUCK) {
        if (sCnt[t] > 0) sGbase[t] = atomicAdd(&cursor[t], sCnt[t]);
        sCnt[t] = 0;
    }
    __syncthreads();
    int kept = sBase[NBUCK];
    // rank + reorder in LDS
#pragma unroll
    for (int k = 0; k < 8; ++k) {
        if (pb[k] >= 0) {
            int r = atomicAdd(&sCnt[pb[k]], 1);
            sReorder[sBase[pb[k]] + r] = pp[k];
        }
    }
    __syncthreads();
    // coalesced flush: binary-search bucket owning slot j
#pragma unroll
    for (int k = 0; k < 8; ++k) {
        int j = t + k * PTHREADS;
        if (j < kept) {
            int lo = 0, hi = NBUCK;
            while (hi - lo > 1) {
                int m = (lo + hi) >> 1;
                if (sBase[m] <= j) lo = m; else hi = m;
            }
            ebuf[sGbase[lo] + (j - sBase[lo])] = sReorder[j];
        }
    }
}

// ---------------- kernel 4: aggregation only (split buckets, deep MLP) ----------------
// 1024 threads = 128 groups of 8 lanes; each edge row fetched as float4 per lane.
// acc rows padded to stride 33 to break the 8-way bank conflict of the q*4+k pattern.
__global__ __launch_bounds__(1024) void k_agg(
        const int* __restrict__ cursor, const int* __restrict__ ebuf,
        const float* __restrict__ y, float* __restrict__ h_pre) {
    __shared__ float acc[256 * 33];
    int t = threadIdx.x;
    for (int j = t; j < 256 * 33; j += 1024) acc[j] = 0.0f;
    __syncthreads();

    const int b  = blockIdx.x / SPLIT;
    const int sl = blockIdx.x % SPLIT;
    const int start = b * CAP;
    const int cnt = cursor[b] - start;
    const int per = (cnt + SPLIT - 1) / SPLIT;
    const int lo = sl * per;
    int hi = lo + per; if (hi > cnt) hi = cnt;

    const int g = t >> 3;           // 128 edge-groups
    const int q = t & 7;            // float4 slot within the 32-float row
    const float4* y4 = (const float4*)y;

    int j = lo + g;
    for (; j + 384 < hi; j += 512) {
        int p0 = ebuf[start + j];
        int p1 = ebuf[start + j + 128];
        int p2 = ebuf[start + j + 256];
        int p3 = ebuf[start + j + 384];
        float4 v0 = y4[(size_t)(p0 & 0x1FFFF) * 8 + q];
        float4 v1 = y4[(size_t)(p1 & 0x1FFFF) * 8 + q];
        float4 v2 = y4[(size_t)(p2 & 0x1FFFF) * 8 + q];
        float4 v3 = y4[(size_t)(p3 & 0x1FFFF) * 8 + q];
        int c0 = ((p0 >> 17) & 255) * 33 + q * 4;
        int c1 = ((p1 >> 17) & 255) * 33 + q * 4;
        int c2 = ((p2 >> 17) & 255) * 33 + q * 4;
        int c3 = ((p3 >> 17) & 255) * 33 + q * 4;
        atomicAdd(&acc[c0 + 0], v0.x); atomicAdd(&acc[c0 + 1], v0.y);
        atomicAdd(&acc[c0 + 2], v0.z); atomicAdd(&acc[c0 + 3], v0.w);
        atomicAdd(&acc[c1 + 0], v1.x); atomicAdd(&acc[c1 + 1], v1.y);
        atomicAdd(&acc[c1 + 2], v1.z); atomicAdd(&acc[c1 + 3], v1.w);
        atomicAdd(&acc[c2 + 0], v2.x); atomicAdd(&acc[c2 + 1], v2.y);
        atomicAdd(&acc[c2 + 2], v2.z); atomicAdd(&acc[c2 + 3], v2.w);
        atomicAdd(&acc[c3 + 0], v3.x); atomicAdd(&acc[c3 + 1], v3.y);
        atomicAdd(&acc[c3 + 2], v3.z); atomicAdd(&acc[c3 + 3], v3.w);
    }
    for (; j < hi; j += 128) {
        int p0 = ebuf[start + j];
        float4 v0 = y4[(size_t)(p0 & 0x1FFFF) * 8 + q];
        int c0 = ((p0 >> 17) & 255) * 33 + q * 4;
        atomicAdd(&acc[c0 + 0], v0.x); atomicAdd(&acc[c0 + 1], v0.y);
        atomicAdd(&acc[c0 + 2], v0.z); atomicAdd(&acc[c0 + 3], v0.w);
    }
    __syncthreads();

    // flush partial sums (agent rows only) to global
    const int c = t & 31, g2 = t >> 5;
    const int nodeBase = b * 256;
    for (int r = g2; r < 256; r += 32) {
        int node = nodeBase + r;
        if (node < N_AGENT)
            atomicAdd(&h_pre[(size_t)node * HID + c], acc[r * 33 + c]);
    }
}

// ---------------- kernel 5: gates + MLP epilogue ----------------
#define EROWS 64
__global__ __launch_bounds__(512) void k_epilogue(
        const int* __restrict__ deg, const float* __restrict__ h_pre,
        const float* __restrict__ y,
        const float* __restrict__ Mz, const float* __restrict__ Mh,
        const float* __restrict__ bz_eff, const float* __restrict__ bh_eff,
        const float* __restrict__ s_ptr,
        const float* __restrict__ W1, const float* __restrict__ b1,
        const float* __restrict__ W2, const float* __restrict__ b2,
        float* __restrict__ out) {
    __shared__ float sMz[1024], sMh[1024], sW1[2048], sW2[6400];
    __shared__ float sbz[32], sbh[32], sb1[64], sb2[100];
    int t = threadIdx.x;
    for (int j = t; j < 1024; j += 512) { sMz[j] = Mz[j]; sMh[j] = Mh[j]; }
    for (int j = t; j < 2048; j += 512) sW1[j] = W1[j];
    for (int j = t; j < 6400; j += 512) sW2[j] = W2[j];
    if (t < 32) { sbz[t] = bz_eff[t]; sbh[t] = bh_eff[t]; }
    if (t >= 64 && t < 128) sb1[t - 64] = b1[t - 64];
    if (t >= 128 && t < 228) sb2[t - 128] = b2[t - 128];
    __syncthreads();

    const float s = *s_ptr;
    const int c = t & 31, g = t >> 5;     // 16 row-groups of 32 lanes
    const int base = blockIdx.x * EROWS;
    for (int r = g; r < EROWS; r += 16) {
        int i = base + r;
        if (i >= N_AGENT) break;
        float di = rsqrtf((float)deg[i] + 1.0f);
        float a = (h_pre[(size_t)i * HID + c] + y[(size_t)i * HID + c]) * di;
        float uz = sbz[c], uh = sbh[c];
#pragma unroll
        for (int k = 0; k < 32; ++k) {
            float ak = __shfl(a, k, 32);
            uz += ak * sMz[k * 32 + c];
            uh += ak * sMh[k * 32 + c];
        }
        float z = 1.0f / (1.0f + expf(-uz));
        float h = s * (1.0f - z) * tanhf(uh);
        h = fmaxf(h, 0.0f);
        float t0 = sb1[c], t1 = sb1[c + 32];
#pragma unroll
        for (int k = 0; k < 32; ++k) {
            float hk = __shfl(h, k, 32);
            t0 += hk * sW1[k * 64 + c];
            t1 += hk * sW1[k * 64 + c + 32];
        }
        t0 = fmaxf(t0, 0.0f); t1 = fmaxf(t1, 0.0f);
        int j3 = (c < 4) ? (c + 96) : 99;
        float o0 = sb2[c];
        float o1 = sb2[c + 32];
        float o2 = sb2[c + 64];
        float o3 = sb2[j3];
#pragma unroll
        for (int k = 0; k < 32; ++k) {
            float ta = __shfl(t0, k, 32);
            float tb = __shfl(t1, k, 32);
            o0 += ta * sW2[k * 100 + c]      + tb * sW2[(k + 32) * 100 + c];
            o1 += ta * sW2[k * 100 + c + 32] + tb * sW2[(k + 32) * 100 + c + 32];
            o2 += ta * sW2[k * 100 + c + 64] + tb * sW2[(k + 32) * 100 + c + 64];
            o3 += ta * sW2[k * 100 + j3]     + tb * sW2[(k + 32) * 100 + j3];
        }
        float* orow = out + (size_t)i * 100;
        orow[c] = o0;
        orow[c + 32] = o1;
        orow[c + 64] = o2;
        if (c < 4) orow[c + 96] = o3;
    }
}

extern "C" void kernel_launch(void* const* d_in, const int* in_sizes, int n_in,
                              void* d_out, int out_size, void* d_ws, size_t ws_size,
                              hipStream_t stream) {
    const float* agent_x = (const float*)d_in[0];
    const float* map_x   = (const float*)d_in[1];
    const int*   ei      = (const int*)d_in[2];
    const float* W_agent = (const float*)d_in[3];
    const float* b_agent = (const float*)d_in[4];
    const float* W_map   = (const float*)d_in[5];
    const float* b_map   = (const float*)d_in[6];
    const float* Wz_c    = (const float*)d_in[7];
    const float* bz_c    = (const float*)d_in[8];
    const float* Wh_c    = (const float*)d_in[11];
    const float* bh_c    = (const float*)d_in[12];
    const float* Wz_l    = (const float*)d_in[13];
    const float* bz_l    = (const float*)d_in[14];
    const float* Wh_l    = (const float*)d_in[17];
    const float* bh_l    = (const float*)d_in[18];
    const float* attn    = (const float*)d_in[19];
    const float* W1      = (const float*)d_in[20];
    const float* b1      = (const float*)d_in[21];
    const float* W2      = (const float*)d_in[22];
    const float* b2      = (const float*)d_in[23];
    float* out = (float*)d_out;

    const int* e_src = ei;
    const int* e_dst = ei + NE;

    // workspace layout (float-element offsets); total ~30.5 MB
    float* ws     = (float*)d_ws;
    float* y      = ws;                          // 3,200,000 (pre-scaled node features)
    float* Mz     = ws + 3200000;                // 1024
    float* Mh     = ws + 3201024;                // 1024
    float* bz     = ws + 3202048;                // 32
    float* bh     = ws + 3202080;                // 32
    float* sS     = ws + 3202112;                // 1 (pad to 3202304)
    int*   deg    = (int*)(ws + 3202304);        // 100,000 (pad to 3302400)
    int*   cursor = (int*)(ws + 3302400);        // 235 (pad to 3302912)
    float* h_pre  = ws + 3302912;                // 60160*32 = 1,925,120 -> 5,228,032
    int*   ebuf   = (int*)(ws + 5228032);        // NBUCK*CAP = 2,406,400 -> end 7,634,432

    hipMemsetAsync(deg, 0, (size_t)N_NODES * sizeof(int), stream);
    hipMemsetAsync(h_pre, 0, (size_t)AGENT_LIM * HID * sizeof(float), stream);

    k_precompute<<<1, 1024, 0, stream>>>(Wz_c, bz_c, Wh_c, bh_c, Wz_l, bz_l,
                                         Wh_l, bh_l, attn, Mz, Mh, bz, bh, sS, cursor);
    k_deg<<<1024, 256, 0, stream>>>(e_dst, deg);
    k_encode<<<(N_NODES * HID + 255) / 256, 256, 0, stream>>>(
        agent_x, map_x, W_agent, b_agent, W_map, b_map, deg, y);
    k_partition<<<(NE + TILE - 1) / TILE, PTHREADS, 0, stream>>>(e_src, e_dst, cursor, ebuf);
    k_agg<<<NBUCK * SPLIT, 1024, 0, stream>>>(cursor, ebuf, y, h_pre);
    k_epilogue<<<(N_AGENT + EROWS - 1) / EROWS, 512, 0, stream>>>(
        deg, h_pre, y, Mz, Mh, bz, bh, sS, W1, b1, W2, b2, out);
}

// Round 2
// 527.612 us; speedup vs baseline: 1.4139x; 1.4139x over previous
//
#include <hip/hip_runtime.h>
#include <math.h>

#define N_AGENT 60000
#define N_MAP   40000
#define N_NODES 100000
#define NE      3200000
#define HID     32
#define PERIODS 30

#define NBUCK     235          // agent-dst scan buckets: ceil(60160/256)
#define AGENT_LIM (NBUCK*256)  // 60160 — dst >= this is pure-map, dropped
#define CSR_CAP   2000000      // kept edges ~1.925M (+85 sigma margin)

// ---------------- kernel 0: fold weights, softmax sum ----------------
__global__ void k_precompute(const float* Wz_c, const float* bz_c,
                             const float* Wh_c, const float* bh_c,
                             const float* Wz_l, const float* bz_l,
                             const float* Wh_l, const float* bh_l,
                             const float* attn,
                             float* Mz, float* Mh, float* bz_eff, float* bh_eff,
                             float* s_out) {
    int t = threadIdx.x;            // blockDim = 1024
    int k = t >> 5, c = t & 31;
    float mz = 0.f, mh = 0.f;
    for (int j = 0; j < HID; ++j) {
        mz += Wz_c[k * HID + j] * Wz_l[j * HID + c];   // Wz_l rows 0..31 (zeros half dead)
        mh += Wh_c[k * HID + j] * Wh_l[j * HID + c];
    }
    Mz[t] = mz; Mh[t] = mh;
    if (t < HID) {
        float bz = bz_l[t], bh = bh_l[t];
        for (int j = 0; j < HID; ++j) {
            bz += bz_c[j] * Wz_l[j * HID + t];
            bh += bh_c[j] * Wh_l[j * HID + t];
        }
        bz_eff[t] = bz; bh_eff[t] = bh;
    }
    if (t == 0) {
        float m = -1e30f;
        for (int i = 0; i < PERIODS; ++i) m = fmaxf(m, attn[i]);
        float S = 0.f;
        for (int i = 0; i < PERIODS; ++i) S += expf(attn[i] - m);
        float s = 0.f;
        for (int i = 0; i < PERIODS; ++i) s += expf(attn[i] - m) / S;
        *s_out = s;
    }
}

// ---------------- kernel 1: in-degree histogram (global atomics) ----------------
__global__ __launch_bounds__(256) void k_deg(const int* __restrict__ dst,
                                             int* __restrict__ deg) {
    int t = blockIdx.x * blockDim.x + threadIdx.x;
    int stride = gridDim.x * blockDim.x;
    const int4* d4 = (const int4*)dst;
    for (int e = t; e < NE / 4; e += stride) {
        int4 d = d4[e];
        atomicAdd(&deg[d.x], 1);
        atomicAdd(&deg[d.y], 1);
        atomicAdd(&deg[d.z], 1);
        atomicAdd(&deg[d.w], 1);
    }
}

// ---------------- kernel 2: node encoders, pre-scaled by dinv[node] ----------------
__global__ void k_encode(const float* __restrict__ agent_x, const float* __restrict__ map_x,
                         const float* __restrict__ W_agent, const float* __restrict__ b_agent,
                         const float* __restrict__ W_map, const float* __restrict__ b_map,
                         const int* __restrict__ deg,
                         float* __restrict__ y) {
    int t = blockIdx.x * blockDim.x + threadIdx.x;
    if (t >= N_NODES * HID) return;
    int i = t >> 5, c = t & 31;
    float acc;
    if (i < N_AGENT) {
        const float* row = agent_x + (size_t)i * 9;
        acc = b_agent[c];
#pragma unroll
        for (int k = 0; k < 9; ++k) acc += row[k] * W_agent[k * HID + c];
    } else {
        const float* row = map_x + (size_t)(i - N_AGENT) * 6;
        acc = b_map[c];
#pragma unroll
        for (int k = 0; k < 6; ++k) acc += row[k] * W_map[k * HID + c];
    }
    float di = rsqrtf((float)deg[i] + 1.0f);
    y[t] = acc * di;                 // fold dinv[src] into the node feature
}

// ---------------- kernel 3a: bucket sums + exclusive scan over 235 buckets ----------------
__global__ __launch_bounds__(256) void k_bsum(const int* __restrict__ deg,
                                              int* __restrict__ bbase) {
    __shared__ int s[256];
    int t = threadIdx.x;
    int sum = 0;
    if (t < NBUCK) {
        const int4* d4 = (const int4*)(deg + t * 256);
        for (int k = 0; k < 64; ++k) { int4 v = d4[k]; sum += v.x + v.y + v.z + v.w; }
    }
    s[t] = sum;
    __syncthreads();
    for (int st = 1; st < 256; st <<= 1) {
        int a = (t >= st) ? s[t - st] : 0;
        __syncthreads();
        s[t] += a;
        __syncthreads();
    }
    if (t < NBUCK) bbase[t] = s[t] - sum;          // exclusive
    if (t == NBUCK - 1) bbase[NBUCK] = s[t];       // total kept edges
}

// ---------------- kernel 3b: per-node exclusive scan -> row_ptr + scatter cursor ----------------
__global__ __launch_bounds__(256) void k_rowptr(const int* __restrict__ deg,
                                                const int* __restrict__ bbase,
                                                int* __restrict__ row_ptr,
                                                int* __restrict__ cur) {
    __shared__ int s[256];
    int b = blockIdx.x, t = threadIdx.x;
    int i = b * 256 + t;
    int v = deg[i];
    s[t] = v;
    __syncthreads();
    for (int st = 1; st < 256; st <<= 1) {
        int a = (t >= st) ? s[t - st] : 0;
        __syncthreads();
        s[t] += a;
        __syncthreads();
    }
    int r = bbase[b] + s[t] - v;
    row_ptr[i] = r;
    cur[i] = r;
    if (b == 0 && t == 0) row_ptr[AGENT_LIM] = bbase[NBUCK];
}

// ---------------- kernel 4: CSR scatter (src into dst's contiguous slot) ----------------
__global__ __launch_bounds__(256) void k_scatter(const int* __restrict__ src,
                                                 const int* __restrict__ dst,
                                                 int* __restrict__ cur,
                                                 int* __restrict__ csr) {
    int t = blockIdx.x * blockDim.x + threadIdx.x;
    int stride = gridDim.x * blockDim.x;
    const int4* s4 = (const int4*)src;
    const int4* d4 = (const int4*)dst;
    for (int e = t; e < NE / 4; e += stride) {
        int4 s = s4[e];
        int4 d = d4[e];
        if (d.x < AGENT_LIM) csr[atomicAdd(&cur[d.x], 1)] = s.x;
        if (d.y < AGENT_LIM) csr[atomicAdd(&cur[d.y], 1)] = s.y;
        if (d.z < AGENT_LIM) csr[atomicAdd(&cur[d.z], 1)] = s.z;
        if (d.w < AGENT_LIM) csr[atomicAdd(&cur[d.w], 1)] = s.w;
    }
}

// ---------------- kernel 5: CSR aggregation, one wave per dst, register accum ----------------
// wave = 8 edge-slots x 8 lanes; each edge row fetched as 8x float4 = 128B coalesced.
// No LDS, no atomics: accumulate in 4 VGPRs, shfl_xor-reduce across the 8 slots, one store.
#define DPW 4     // dsts per wave
__global__ __launch_bounds__(256) void k_agg(const int* __restrict__ row_ptr,
                                             const int* __restrict__ csr,
                                             const float* __restrict__ y,
                                             float* __restrict__ h_pre) {
    int t = threadIdx.x;
    int w = t >> 6, lane = t & 63;
    int g = lane >> 3, q = lane & 7;
    const float4* y4 = (const float4*)y;
    float4* h4 = (float4*)h_pre;
    int base = blockIdx.x * (4 * DPW) + w * DPW;

    for (int k = 0; k < DPW; ++k) {
        int i = base + k;
        int e0 = row_ptr[i], e1 = row_ptr[i + 1];
        float ax = 0.f, ay = 0.f, az = 0.f, aw = 0.f;
        int j = e0 + g;
        for (; j + 8 < e1; j += 16) {
            int s0 = csr[j];
            int s1 = csr[j + 8];
            float4 v0 = y4[(size_t)s0 * 8 + q];
            float4 v1 = y4[(size_t)s1 * 8 + q];
            ax += v0.x + v1.x;
            ay += v0.y + v1.y;
            az += v0.z + v1.z;
            aw += v0.w + v1.w;
        }
        if (j < e1) {
            int s0 = csr[j];
            float4 v0 = y4[(size_t)s0 * 8 + q];
            ax += v0.x; ay += v0.y; az += v0.z; aw += v0.w;
        }
        // reduce across the 8 edge-slots (lane bits 3..5)
#pragma unroll
        for (int off = 8; off <= 32; off <<= 1) {
            ax += __shfl_xor(ax, off, 64);
            ay += __shfl_xor(ay, off, 64);
            az += __shfl_xor(az, off, 64);
            aw += __shfl_xor(aw, off, 64);
        }
        if (g == 0) h4[(size_t)i * 8 + q] = make_float4(ax, ay, az, aw);
    }
}

// ---------------- kernel 6: gates + MLP epilogue ----------------
#define EROWS 64
__global__ __launch_bounds__(512) void k_epilogue(
        const int* __restrict__ deg, const float* __restrict__ h_pre,
        const float* __restrict__ y,
        const float* __restrict__ Mz, const float* __restrict__ Mh,
        const float* __restrict__ bz_eff, const float* __restrict__ bh_eff,
        const float* __restrict__ s_ptr,
        const float* __restrict__ W1, const float* __restrict__ b1,
        const float* __restrict__ W2, const float* __restrict__ b2,
        float* __restrict__ out) {
    __shared__ float sMz[1024], sMh[1024], sW1[2048], sW2[6400];
    __shared__ float sbz[32], sbh[32], sb1[64], sb2[100];
    int t = threadIdx.x;
    for (int j = t; j < 1024; j += 512) { sMz[j] = Mz[j]; sMh[j] = Mh[j]; }
    for (int j = t; j < 2048; j += 512) sW1[j] = W1[j];
    for (int j = t; j < 6400; j += 512) sW2[j] = W2[j];
    if (t < 32) { sbz[t] = bz_eff[t]; sbh[t] = bh_eff[t]; }
    if (t >= 64 && t < 128) sb1[t - 64] = b1[t - 64];
    if (t >= 128 && t < 228) sb2[t - 128] = b2[t - 128];
    __syncthreads();

    const float s = *s_ptr;
    const int c = t & 31, g = t >> 5;     // 16 row-groups of 32 lanes
    const int base = blockIdx.x * EROWS;
    for (int r = g; r < EROWS; r += 16) {
        int i = base + r;
        if (i >= N_AGENT) break;
        float di = rsqrtf((float)deg[i] + 1.0f);
        float a = (h_pre[(size_t)i * HID + c] + y[(size_t)i * HID + c]) * di;
        float uz = sbz[c], uh = sbh[c];
#pragma unroll
        for (int k = 0; k < 32; ++k) {
            float ak = __shfl(a, k, 32);
            uz += ak * sMz[k * 32 + c];
            uh += ak * sMh[k * 32 + c];
        }
        float z = 1.0f / (1.0f + expf(-uz));
        float h = s * (1.0f - z) * tanhf(uh);
        h = fmaxf(h, 0.0f);
        float t0 = sb1[c], t1 = sb1[c + 32];
#pragma unroll
        for (int k = 0; k < 32; ++k) {
            float hk = __shfl(h, k, 32);
            t0 += hk * sW1[k * 64 + c];
            t1 += hk * sW1[k * 64 + c + 32];
        }
        t0 = fmaxf(t0, 0.0f); t1 = fmaxf(t1, 0.0f);
        int j3 = (c < 4) ? (c + 96) : 99;
        float o0 = sb2[c];
        float o1 = sb2[c + 32];
        float o2 = sb2[c + 64];
        float o3 = sb2[j3];
#pragma unroll
        for (int k = 0; k < 32; ++k) {
            float ta = __shfl(t0, k, 32);
            float tb = __shfl(t1, k, 32);
            o0 += ta * sW2[k * 100 + c]      + tb * sW2[(k + 32) * 100 + c];
            o1 += ta * sW2[k * 100 + c + 32] + tb * sW2[(k + 32) * 100 + c + 32];
            o2 += ta * sW2[k * 100 + c + 64] + tb * sW2[(k + 32) * 100 + c + 64];
            o3 += ta * sW2[k * 100 + j3]     + tb * sW2[(k + 32) * 100 + j3];
        }
        float* orow = out + (size_t)i * 100;
        orow[c] = o0;
        orow[c + 32] = o1;
        orow[c + 64] = o2;
        if (c < 4) orow[c + 96] = o3;
    }
}

extern "C" void kernel_launch(void* const* d_in, const int* in_sizes, int n_in,
                              void* d_out, int out_size, void* d_ws, size_t ws_size,
                              hipStream_t stream) {
    const float* agent_x = (const float*)d_in[0];
    const float* map_x   = (const float*)d_in[1];
    const int*   ei      = (const int*)d_in[2];
    const float* W_agent = (const float*)d_in[3];
    const float* b_agent = (const float*)d_in[4];
    const float* W_map   = (const float*)d_in[5];
    const float* b_map   = (const float*)d_in[6];
    const float* Wz_c    = (const float*)d_in[7];
    const float* bz_c    = (const float*)d_in[8];
    const float* Wh_c    = (const float*)d_in[11];
    const float* bh_c    = (const float*)d_in[12];
    const float* Wz_l    = (const float*)d_in[13];
    const float* bz_l    = (const float*)d_in[14];
    const float* Wh_l    = (const float*)d_in[17];
    const float* bh_l    = (const float*)d_in[18];
    const float* attn    = (const float*)d_in[19];
    const float* W1      = (const float*)d_in[20];
    const float* b1      = (const float*)d_in[21];
    const float* W2      = (const float*)d_in[22];
    const float* b2      = (const float*)d_in[23];
    float* out = (float*)d_out;

    const int* e_src = ei;
    const int* e_dst = ei + NE;

    // workspace layout (float-element offsets); total ~29.4 MB
    float* ws      = (float*)d_ws;
    float* y       = ws;                          // 3,200,000 (pre-scaled node features)
    float* Mz      = ws + 3200000;                // 1024
    float* Mh      = ws + 3201024;                // 1024
    float* bz      = ws + 3202048;                // 32
    float* bh      = ws + 3202080;                // 32
    float* sS      = ws + 3202112;                // 1 (pad to 3202304)
    int*   deg     = (int*)(ws + 3202304);        // 100,000 (pad to 3302400)
    int*   bbase   = (int*)(ws + 3302400);        // 236 (pad to 3302912)
    int*   row_ptr = (int*)(ws + 3302912);        // 60,161 (pad to 3363328)
    int*   cur     = (int*)(ws + 3363328);        // 60,160 (pad to 3423744)
    float* h_pre   = ws + 3423744;                // 60160*32 = 1,925,120 -> 5,348,864
    int*   csr     = (int*)(ws + 5348864);        // 2,000,000 -> end 7,348,864

    hipMemsetAsync(deg, 0, (size_t)N_NODES * sizeof(int), stream);

    k_precompute<<<1, 1024, 0, stream>>>(Wz_c, bz_c, Wh_c, bh_c, Wz_l, bz_l,
                                         Wh_l, bh_l, attn, Mz, Mh, bz, bh, sS);
    k_deg<<<1024, 256, 0, stream>>>(e_dst, deg);
    k_encode<<<(N_NODES * HID + 255) / 256, 256, 0, stream>>>(
        agent_x, map_x, W_agent, b_agent, W_map, b_map, deg, y);
    k_bsum<<<1, 256, 0, stream>>>(deg, bbase);
    k_rowptr<<<NBUCK, 256, 0, stream>>>(deg, bbase, row_ptr, cur);
    k_scatter<<<1024, 256, 0, stream>>>(e_src, e_dst, cur, csr);
    k_agg<<<AGENT_LIM / (4 * DPW), 256, 0, stream>>>(row_ptr, csr, y, h_pre);
    k_epilogue<<<(N_AGENT + EROWS - 1) / EROWS, 512, 0, stream>>>(
        deg, h_pre, y, Mz, Mh, bz, bh, sS, W1, b1, W2, b2, out);
}

// Round 4
// 349.012 us; speedup vs baseline: 2.1375x; 1.5117x over previous
//
#include <hip/hip_runtime.h>
#include <math.h>

#define N_AGENT 60000
#define N_MAP   40000
#define N_NODES 100000
#define NE      3200000
#define HID     32
#define PERIODS 30

#define NBUCK   391        // ceil(100000/256) buckets of 256 dst nodes
#define NABUCK  235        // buckets containing agent dsts
#define CAP     10240      // per-bucket capacity (mean 8192, +22 sigma)
#define TILE    4096       // edges per partition block
#define PTHREADS 512
#define ABLK    64         // dsts per k_aggmlp block

// ---------------- kernel 0: fold weights, softmax sum, cursor init ----------------
__global__ void k_precompute(const float* Wz_c, const float* bz_c,
                             const float* Wh_c, const float* bh_c,
                             const float* Wz_l, const float* bz_l,
                             const float* Wh_l, const float* bh_l,
                             const float* attn,
                             float* Mz, float* Mh, float* bz_eff, float* bh_eff,
                             float* s_out, int* cursor) {
    int t = threadIdx.x;            // blockDim = 1024
    int k = t >> 5, c = t & 31;
    float mz = 0.f, mh = 0.f;
    for (int j = 0; j < HID; ++j) {
        mz += Wz_c[k * HID + j] * Wz_l[j * HID + c];   // Wz_l rows 0..31 (zeros half dead)
        mh += Wh_c[k * HID + j] * Wh_l[j * HID + c];
    }
    Mz[t] = mz; Mh[t] = mh;
    if (t < NBUCK) cursor[t] = t * CAP;
    if (t < HID) {
        float bz = bz_l[t], bh = bh_l[t];
        for (int j = 0; j < HID; ++j) {
            bz += bz_c[j] * Wz_l[j * HID + t];
            bh += bh_c[j] * Wh_l[j * HID + t];
        }
        bz_eff[t] = bz; bh_eff[t] = bh;
    }
    if (t == 0) {
        float m = -1e30f;
        for (int i = 0; i < PERIODS; ++i) m = fmaxf(m, attn[i]);
        float S = 0.f;
        for (int i = 0; i < PERIODS; ++i) S += expf(attn[i] - m);
        float s = 0.f;
        for (int i = 0; i < PERIODS; ++i) s += expf(attn[i] - m) / S;
        *s_out = s;
    }
}

// ---------------- kernel 1: LDS-staged multisplit partition (all edges) ----------------
// pack = src | (dst_low << 17); bucket = dst >> 8
__global__ __launch_bounds__(PTHREADS) void k_partition(
        const int* __restrict__ src, const int* __restrict__ dst,
        int* __restrict__ cursor, int* __restrict__ ebuf) {
    __shared__ int sCnt[NBUCK + 1];
    __shared__ int sBase[NBUCK + 1];
    __shared__ int sGbase[NBUCK];
    __shared__ int sScan[PTHREADS];
    __shared__ int sReorder[TILE];
    int t = threadIdx.x;
    int tileBase = blockIdx.x * TILE;
    int tcount = NE - tileBase; if (tcount > TILE) tcount = TILE;

    if (t < NBUCK) sCnt[t] = 0;
    __syncthreads();

    int pb[8]; int pp[8];
#pragma unroll
    for (int k = 0; k < 8; ++k) {
        int e = tileBase + t + k * PTHREADS;
        pb[k] = -1;
        if (e < NE) {
            int s = src[e], d = dst[e];
            pb[k] = d >> 8;
            pp[k] = s | ((d & 255) << 17);
            atomicAdd(&sCnt[pb[k]], 1);
        }
    }
    __syncthreads();

    // inclusive scan of sCnt via sScan (Hillis-Steele over 512 threads)
    int v = (t < NBUCK) ? sCnt[t] : 0;
    sScan[t] = v;
    __syncthreads();
    for (int s = 1; s < PTHREADS; s <<= 1) {
        int a = (t >= s) ? sScan[t - s] : 0;
        __syncthreads();
        sScan[t] += a;
        __syncthreads();
    }
    if (t <= NBUCK) sBase[t] = sScan[t] - v;   // exclusive; sBase[NBUCK] = tile total
    __syncthreads();
    // reserve global space, reset counters for rank pass
    if (t < NBUCK) {
        if (sCnt[t] > 0) sGbase[t] = atomicAdd(&cursor[t], sCnt[t]);
        sCnt[t] = 0;
    }
    __syncthreads();
    // rank + reorder in LDS
#pragma unroll
    for (int k = 0; k < 8; ++k) {
        if (pb[k] >= 0) {
            int r = atomicAdd(&sCnt[pb[k]], 1);
            sReorder[sBase[pb[k]] + r] = pp[k];
        }
    }
    __syncthreads();
    // coalesced flush: binary-search bucket owning slot j
#pragma unroll
    for (int k = 0; k < 8; ++k) {
        int j = t + k * PTHREADS;
        if (j < tcount) {
            int lo = 0, hi = NBUCK;
            while (hi - lo > 1) {
                int m = (lo + hi) >> 1;
                if (sBase[m] <= j) lo = m; else hi = m;
            }
            ebuf[sGbase[lo] + (j - sBase[lo])] = sReorder[j];
        }
    }
}

// ---------------- kernel 2: per-bucket degree histogram (LDS atomics only) ----------------
__global__ __launch_bounds__(256) void k_hist(const int* __restrict__ cursor,
                                              const int* __restrict__ ebuf,
                                              int* __restrict__ deg) {
    __shared__ int h[256];
    int t = threadIdx.x;
    int b = blockIdx.x;
    h[t] = 0;
    __syncthreads();
    int start = b * CAP;
    int cnt = cursor[b] - start;
    for (int j = t; j < cnt; j += 256)
        atomicAdd(&h[(ebuf[start + j] >> 17) & 255], 1);
    __syncthreads();
    int node = b * 256 + t;
    if (node < N_NODES) deg[node] = h[t];
}

// ---------------- kernel 3: node encoders, pre-scaled by dinv[node] ----------------
__global__ void k_encode(const float* __restrict__ agent_x, const float* __restrict__ map_x,
                         const float* __restrict__ W_agent, const float* __restrict__ b_agent,
                         const float* __restrict__ W_map, const float* __restrict__ b_map,
                         const int* __restrict__ deg,
                         float* __restrict__ y) {
    int t = blockIdx.x * blockDim.x + threadIdx.x;
    if (t >= N_NODES * HID) return;
    int i = t >> 5, c = t & 31;
    float acc;
    if (i < N_AGENT) {
        const float* row = agent_x + (size_t)i * 9;
        acc = b_agent[c];
#pragma unroll
        for (int k = 0; k < 9; ++k) acc += row[k] * W_agent[k * HID + c];
    } else {
        const float* row = map_x + (size_t)(i - N_AGENT) * 6;
        acc = b_map[c];
#pragma unroll
        for (int k = 0; k < 6; ++k) acc += row[k] * W_map[k * HID + c];
    }
    float di = rsqrtf((float)deg[i] + 1.0f);
    y[t] = acc * di;                 // fold dinv[src] into the node feature
}

// ---------------- kernel 4: per-bucket in-place CSR sort (agent buckets only) ----------
// scan deg -> local row offsets; rank-reorder packed edges; write back src-only, sorted.
__global__ __launch_bounds__(1024) void k_sortlocal(
        const int* __restrict__ cursor, int* __restrict__ ebuf,
        const int* __restrict__ deg, int* __restrict__ row_start) {
    __shared__ int sSorted[CAP];          // 40 KB
    __shared__ int sBase[256];
    __shared__ int sCnt[256];
    __shared__ int sScan[256];
    int t = threadIdx.x;
    const int b = blockIdx.x;
    const int nodeBase = b * 256;

    int d0 = 0;
    if (t < 256) {
        d0 = deg[nodeBase + t];
        sCnt[t] = 0;
        sScan[t] = d0;
    }
    __syncthreads();
    for (int st = 1; st < 256; st <<= 1) {
        int a = 0;
        if (t < 256 && t >= st) a = sScan[t - st];
        __syncthreads();
        if (t < 256) sScan[t] += a;
        __syncthreads();
    }
    if (t < 256) {
        sBase[t] = sScan[t] - d0;
        row_start[nodeBase + t] = b * CAP + sBase[t];
    }
    __syncthreads();

    const int start = b * CAP;
    const int cnt = cursor[b] - start;
    for (int j = t; j < cnt; j += 1024) {
        int p = ebuf[start + j];
        int dl = (p >> 17) & 255;
        int r = atomicAdd(&sCnt[dl], 1);
        sSorted[sBase[dl] + r] = p & 0x1FFFF;
    }
    __syncthreads();
    for (int j = t; j < cnt; j += 1024)
        ebuf[start + j] = sSorted[j];      // in place: block owns this range
}

// ---------------- kernel 5: fused CSR gather + gates + MLP ----------------
// 1024 thr = 16 waves; each wave 4 dsts (8 edge-slots x 8 lanes, float4, x4 in flight).
// ~51 KB LDS -> 2 blocks/CU, 32 waves/CU.
__global__ __launch_bounds__(1024) void k_aggmlp(
        const int* __restrict__ row_start, const int* __restrict__ deg,
        const int* __restrict__ ebuf, const float* __restrict__ y,
        const float* __restrict__ Mz, const float* __restrict__ Mh,
        const float* __restrict__ bz_eff, const float* __restrict__ bh_eff,
        const float* __restrict__ s_ptr,
        const float* __restrict__ W1, const float* __restrict__ b1,
        const float* __restrict__ W2, const float* __restrict__ b2,
        float* __restrict__ out) {
    __shared__ float sAcc[ABLK * 32];     // 8 KB
    __shared__ float sMz[1024], sMh[1024], sW1[2048], sW2[6400];
    __shared__ float sbz[32], sbh[32], sb1[64], sb2[100];
    int t = threadIdx.x;
    sMz[t] = Mz[t]; sMh[t] = Mh[t];
    for (int j = t; j < 2048; j += 1024) sW1[j] = W1[j];
    for (int j = t; j < 6400; j += 1024) sW2[j] = W2[j];
    if (t < 32) { sbz[t] = bz_eff[t]; sbh[t] = bh_eff[t]; }
    if (t >= 32 && t < 96) sb1[t - 32] = b1[t - 32];
    if (t >= 128 && t < 228) sb2[t - 128] = b2[t - 128];

    const int nodeBase = blockIdx.x * ABLK;
    const int w = t >> 6, lane = t & 63;
    const int g = lane >> 3, q = lane & 7;
    const float4* y4 = (const float4*)y;

#pragma unroll
    for (int k = 0; k < 4; ++k) {
        int r = w * 4 + k;
        int i = nodeBase + r;
        if (i >= N_AGENT) break;          // wave-uniform
        int e0 = row_start[i];
        int e1 = e0 + deg[i];
        float ax = 0.f, ay = 0.f, az = 0.f, aw = 0.f;
        int j = e0 + g;
        for (; j + 24 < e1; j += 32) {
            int s0 = ebuf[j];
            int s1 = ebuf[j + 8];
            int s2 = ebuf[j + 16];
            int s3 = ebuf[j + 24];
            float4 v0 = y4[(size_t)s0 * 8 + q];
            float4 v1 = y4[(size_t)s1 * 8 + q];
            float4 v2 = y4[(size_t)s2 * 8 + q];
            float4 v3 = y4[(size_t)s3 * 8 + q];
            ax += (v0.x + v1.x) + (v2.x + v3.x);
            ay += (v0.y + v1.y) + (v2.y + v3.y);
            az += (v0.z + v1.z) + (v2.z + v3.z);
            aw += (v0.w + v1.w) + (v2.w + v3.w);
        }
        for (; j < e1; j += 8) {
            int s0 = ebuf[j];
            float4 v0 = y4[(size_t)s0 * 8 + q];
            ax += v0.x; ay += v0.y; az += v0.z; aw += v0.w;
        }
#pragma unroll
        for (int off = 8; off <= 32; off <<= 1) {
            ax += __shfl_xor(ax, off, 64);
            ay += __shfl_xor(ay, off, 64);
            az += __shfl_xor(az, off, 64);
            aw += __shfl_xor(aw, off, 64);
        }
        if (g == 0)
            *(float4*)&sAcc[r * 32 + q * 4] = make_float4(ax, ay, az, aw);
    }
    __syncthreads();

    // epilogue: 32 groups of 32 lanes, 2 rows each
    const float s = *s_ptr;
    const int c = t & 31, g2 = t >> 5;
    for (int r = g2; r < ABLK; r += 32) {
        int i = nodeBase + r;
        if (i >= N_AGENT) break;
        float di = rsqrtf((float)deg[i] + 1.0f);
        float a = (sAcc[r * 32 + c] + y[(size_t)i * HID + c]) * di;
        float uz = sbz[c], uh = sbh[c];
#pragma unroll
        for (int k = 0; k < 32; ++k) {
            float ak = __shfl(a, k, 32);
            uz += ak * sMz[k * 32 + c];
            uh += ak * sMh[k * 32 + c];
        }
        float z = 1.0f / (1.0f + expf(-uz));
        float h = s * (1.0f - z) * tanhf(uh);
        h = fmaxf(h, 0.0f);
        float t0 = sb1[c], t1 = sb1[c + 32];
#pragma unroll
        for (int k = 0; k < 32; ++k) {
            float hk = __shfl(h, k, 32);
            t0 += hk * sW1[k * 64 + c];
            t1 += hk * sW1[k * 64 + c + 32];
        }
        t0 = fmaxf(t0, 0.0f); t1 = fmaxf(t1, 0.0f);
        int j3 = (c < 4) ? (c + 96) : 99;
        float o0 = sb2[c];
        float o1 = sb2[c + 32];
        float o2 = sb2[c + 64];
        float o3 = sb2[j3];
#pragma unroll
        for (int k = 0; k < 32; ++k) {
            float ta = __shfl(t0, k, 32);
            float tb = __shfl(t1, k, 32);
            o0 += ta * sW2[k * 100 + c]      + tb * sW2[(k + 32) * 100 + c];
            o1 += ta * sW2[k * 100 + c + 32] + tb * sW2[(k + 32) * 100 + c + 32];
            o2 += ta * sW2[k * 100 + c + 64] + tb * sW2[(k + 32) * 100 + c + 64];
            o3 += ta * sW2[k * 100 + j3]     + tb * sW2[(k + 32) * 100 + j3];
        }
        float* orow = out + (size_t)i * 100;
        orow[c] = o0;
        orow[c + 32] = o1;
        orow[c + 64] = o2;
        if (c < 4) orow[c + 96] = o3;
    }
}

extern "C" void kernel_launch(void* const* d_in, const int* in_sizes, int n_in,
                              void* d_out, int out_size, void* d_ws, size_t ws_size,
                              hipStream_t stream) {
    const float* agent_x = (const float*)d_in[0];
    const float* map_x   = (const float*)d_in[1];
    const int*   ei      = (const int*)d_in[2];
    const float* W_agent = (const float*)d_in[3];
    const float* b_agent = (const float*)d_in[4];
    const float* W_map   = (const float*)d_in[5];
    const float* b_map   = (const float*)d_in[6];
    const float* Wz_c    = (const float*)d_in[7];
    const float* bz_c    = (const float*)d_in[8];
    const float* Wh_c    = (const float*)d_in[11];
    const float* bh_c    = (const float*)d_in[12];
    const float* Wz_l    = (const float*)d_in[13];
    const float* bz_l    = (const float*)d_in[14];
    const float* Wh_l    = (const float*)d_in[17];
    const float* bh_l    = (const float*)d_in[18];
    const float* attn    = (const float*)d_in[19];
    const float* W1      = (const float*)d_in[20];
    const float* b1      = (const float*)d_in[21];
    const float* W2      = (const float*)d_in[22];
    const float* b2      = (const float*)d_in[23];
    float* out = (float*)d_out;

    const int* e_src = ei;
    const int* e_dst = ei + NE;

    // workspace layout (float-element offsets); total ~29.5 MB
    float* ws       = (float*)d_ws;
    float* y        = ws;                          // 3,200,000 (pre-scaled node features)
    float* Mz       = ws + 3200000;                // 1024
    float* Mh       = ws + 3201024;                // 1024
    float* bz       = ws + 3202048;                // 32
    float* bh       = ws + 3202080;                // 32
    float* sS       = ws + 3202112;                // 1 (pad to 3202304)
    int*   deg      = (int*)(ws + 3202304);        // 100,000 (pad to 3302400)
    int*   cursor   = (int*)(ws + 3302400);        // 391 (pad to 3302912)
    int*   row_start= (int*)(ws + 3302912);        // 60,160 (pad to 3363328)
    int*   ebuf     = (int*)(ws + 3363328);        // NBUCK*CAP = 4,003,840 -> end 7,367,168

    k_precompute<<<1, 1024, 0, stream>>>(Wz_c, bz_c, Wh_c, bh_c, Wz_l, bz_l,
                                         Wh_l, bh_l, attn, Mz, Mh, bz, bh, sS, cursor);
    k_partition<<<(NE + TILE - 1) / TILE, PTHREADS, 0, stream>>>(e_src, e_dst, cursor, ebuf);
    k_hist<<<NBUCK, 256, 0, stream>>>(cursor, ebuf, deg);
    k_encode<<<(N_NODES * HID + 255) / 256, 256, 0, stream>>>(
        agent_x, map_x, W_agent, b_agent, W_map, b_map, deg, y);
    k_sortlocal<<<NABUCK, 1024, 0, stream>>>(cursor, ebuf, deg, row_start);
    k_aggmlp<<<(N_AGENT + ABLK - 1) / ABLK, 1024, 0, stream>>>(
        row_start, deg, ebuf, y, Mz, Mh, bz, bh, sS, W1, b1, W2, b2, out);
}

// Round 5
// 332.076 us; speedup vs baseline: 2.2465x; 1.0510x over previous
//
#include <hip/hip_runtime.h>
#include <math.h>

#define N_AGENT 60000
#define N_MAP   40000
#define N_NODES 100000
#define NE      3200000
#define HID     32
#define PERIODS 30

#define NBUCK   391        // ceil(100000/256) buckets of 256 dst nodes
#define NABUCK  235        // buckets containing agent dsts
#define CAP     10240      // per-bucket capacity (mean 8192, +22 sigma)
#define TILE    4096       // edges per partition block
#define PTHREADS 512
#define ABLK    64         // dsts per k_aggmlp block
#define EBLK    4096       // staged edges per k_aggmlp block (mean 2048, sigma 45)

// ---------------- kernel 0: fold weights, softmax sum, cursor init ----------------
__global__ void k_precompute(const float* Wz_c, const float* bz_c,
                             const float* Wh_c, const float* bh_c,
                             const float* Wz_l, const float* bz_l,
                             const float* Wh_l, const float* bh_l,
                             const float* attn,
                             float* Mz, float* Mh, float* bz_eff, float* bh_eff,
                             float* s_out, int* cursor) {
    int t = threadIdx.x;            // blockDim = 1024
    int k = t >> 5, c = t & 31;
    float mz = 0.f, mh = 0.f;
    for (int j = 0; j < HID; ++j) {
        mz += Wz_c[k * HID + j] * Wz_l[j * HID + c];   // Wz_l rows 0..31 (zeros half dead)
        mh += Wh_c[k * HID + j] * Wh_l[j * HID + c];
    }
    Mz[t] = mz; Mh[t] = mh;
    if (t < NBUCK) cursor[t] = t * CAP;
    if (t < HID) {
        float bz = bz_l[t], bh = bh_l[t];
        for (int j = 0; j < HID; ++j) {
            bz += bz_c[j] * Wz_l[j * HID + t];
            bh += bh_c[j] * Wh_l[j * HID + t];
        }
        bz_eff[t] = bz; bh_eff[t] = bh;
    }
    if (t == 0) {
        float m = -1e30f;
        for (int i = 0; i < PERIODS; ++i) m = fmaxf(m, attn[i]);
        float S = 0.f;
        for (int i = 0; i < PERIODS; ++i) S += expf(attn[i] - m);
        float s = 0.f;
        for (int i = 0; i < PERIODS; ++i) s += expf(attn[i] - m) / S;
        *s_out = s;
    }
}

// ---------------- kernel 1: LDS-staged multisplit partition (all edges) ----------------
// pack = src | (dst_low << 17); bucket = dst >> 8
// one-pass rank: first LDS atomic returns the local rank; int4-vectorized edge loads.
__global__ __launch_bounds__(PTHREADS) void k_partition(
        const int* __restrict__ src, const int* __restrict__ dst,
        int* __restrict__ cursor, int* __restrict__ ebuf) {
    __shared__ int sCnt[NBUCK];
    __shared__ int sBase[NBUCK + 1];
    __shared__ int sGbase[NBUCK];
    __shared__ int sScan[PTHREADS];
    __shared__ int sReorder[TILE];
    int t = threadIdx.x;
    int tileBase = blockIdx.x * TILE;
    int tcount = NE - tileBase; if (tcount > TILE) tcount = TILE;

    if (t < NBUCK) sCnt[t] = 0;
    __syncthreads();

    int pb[8], pp[8], pr[8];
    const int4* s4 = (const int4*)src;
    const int4* d4 = (const int4*)dst;
#pragma unroll
    for (int k = 0; k < 2; ++k) {
        int e4 = (tileBase >> 2) + t + k * PTHREADS;
        int valid = (e4 << 2) < NE;
        int4 sv, dv;
        if (valid) { sv = s4[e4]; dv = d4[e4]; }
#define PROC(m, SS, DD) { int kk = k * 4 + m;                                  \
        if (valid) { pb[kk] = (DD) >> 8;                                       \
                     pp[kk] = (SS) | (((DD) & 255) << 17);                     \
                     pr[kk] = atomicAdd(&sCnt[pb[kk]], 1); }                   \
        else pb[kk] = -1; }
        PROC(0, sv.x, dv.x)
        PROC(1, sv.y, dv.y)
        PROC(2, sv.z, dv.z)
        PROC(3, sv.w, dv.w)
#undef PROC
    }
    __syncthreads();

    // inclusive scan of sCnt via sScan (Hillis-Steele over 512 threads)
    int v = (t < NBUCK) ? sCnt[t] : 0;
    sScan[t] = v;
    __syncthreads();
    for (int s = 1; s < PTHREADS; s <<= 1) {
        int a = (t >= s) ? sScan[t - s] : 0;
        __syncthreads();
        sScan[t] += a;
        __syncthreads();
    }
    if (t <= NBUCK) sBase[t] = sScan[t] - v;   // exclusive; sBase[NBUCK] = tile total
    __syncthreads();
    // reserve global space
    if (t < NBUCK && sCnt[t] > 0) sGbase[t] = atomicAdd(&cursor[t], sCnt[t]);
    __syncthreads();
    // place by saved rank
#pragma unroll
    for (int k = 0; k < 8; ++k) {
        if (pb[k] >= 0) sReorder[sBase[pb[k]] + pr[k]] = pp[k];
    }
    __syncthreads();
    // coalesced flush: binary-search bucket owning slot j
#pragma unroll
    for (int k = 0; k < 8; ++k) {
        int j = t + k * PTHREADS;
        if (j < tcount) {
            int lo = 0, hi = NBUCK;
            while (hi - lo > 1) {
                int m = (lo + hi) >> 1;
                if (sBase[m] <= j) lo = m; else hi = m;
            }
            ebuf[sGbase[lo] + (j - sBase[lo])] = sReorder[j];
        }
    }
}

// ---------------- kernel 2: per-bucket degree histogram (LDS atomics only) ----------------
__global__ __launch_bounds__(256) void k_hist(const int* __restrict__ cursor,
                                              const int* __restrict__ ebuf,
                                              int* __restrict__ deg) {
    __shared__ int h[256];
    int t = threadIdx.x;
    int b = blockIdx.x;
    h[t] = 0;
    __syncthreads();
    int start = b * CAP;
    int cnt = cursor[b] - start;
    for (int j = t; j < cnt; j += 256)
        atomicAdd(&h[(ebuf[start + j] >> 17) & 255], 1);
    __syncthreads();
    int node = b * 256 + t;
    if (node < N_NODES) deg[node] = h[t];
}

// ---------------- kernel 3: node encoders, pre-scaled by dinv; zero row at N_NODES ------
__global__ void k_encode(const float* __restrict__ agent_x, const float* __restrict__ map_x,
                         const float* __restrict__ W_agent, const float* __restrict__ b_agent,
                         const float* __restrict__ W_map, const float* __restrict__ b_map,
                         const int* __restrict__ deg,
                         float* __restrict__ y) {
    int t = blockIdx.x * blockDim.x + threadIdx.x;
    if (t >= (N_NODES + 1) * HID) return;
    int i = t >> 5, c = t & 31;
    float acc = 0.f;
    if (i < N_AGENT) {
        float v = (c < 9) ? agent_x[(size_t)i * 9 + c] : 0.f;
        acc = b_agent[c];
#pragma unroll
        for (int k = 0; k < 9; ++k) acc += __shfl(v, k, 32) * W_agent[k * HID + c];
        acc *= rsqrtf((float)deg[i] + 1.0f);
    } else if (i < N_NODES) {
        float v = (c < 6) ? map_x[(size_t)(i - N_AGENT) * 6 + c] : 0.f;
        acc = b_map[c];
#pragma unroll
        for (int k = 0; k < 6; ++k) acc += __shfl(v, k, 32) * W_map[k * HID + c];
        acc *= rsqrtf((float)deg[i] + 1.0f);
    }
    y[t] = acc;                       // i == N_NODES -> zero row (gather sink)
}

// ---------------- kernel 4: per-bucket in-place CSR sort (agent buckets only) ----------
__global__ __launch_bounds__(1024) void k_sortlocal(
        const int* __restrict__ cursor, int* __restrict__ ebuf,
        const int* __restrict__ deg, int* __restrict__ row_start) {
    __shared__ int sSorted[CAP];          // 40 KB
    __shared__ int sBase[256];
    __shared__ int sCnt[256];
    __shared__ int sScan[256];
    int t = threadIdx.x;
    const int b = blockIdx.x;
    const int nodeBase = b * 256;

    int d0 = 0;
    if (t < 256) {
        d0 = deg[nodeBase + t];
        sCnt[t] = 0;
        sScan[t] = d0;
    }
    __syncthreads();
    for (int st = 1; st < 256; st <<= 1) {
        int a = 0;
        if (t < 256 && t >= st) a = sScan[t - st];
        __syncthreads();
        if (t < 256) sScan[t] += a;
        __syncthreads();
    }
    if (t < 256) {
        sBase[t] = sScan[t] - d0;
        row_start[nodeBase + t] = b * CAP + sBase[t];
    }
    __syncthreads();

    const int start = b * CAP;
    const int cnt = cursor[b] - start;
    for (int j = t; j < cnt; j += 1024) {
        int p = ebuf[start + j];
        int dl = (p >> 17) & 255;
        int r = atomicAdd(&sCnt[dl], 1);
        sSorted[sBase[dl] + r] = p & 0x1FFFF;
    }
    __syncthreads();
    for (int j = t; j < cnt; j += 1024)
        ebuf[start + j] = sSorted[j];      // in place: block owns this range
}

// ---------------- kernel 5: fused CSR gather + gates + MLP ----------------
// Edges staged in LDS; gather loop always runs the 4-deep unroll via predicated
// indices into a zero row at y[N_NODES]. 4 independent 128B gathers in flight/lane.
__global__ __launch_bounds__(1024) void k_aggmlp(
        const int* __restrict__ row_start, const int* __restrict__ deg,
        const int* __restrict__ ebuf, const float* __restrict__ y,
        const float* __restrict__ Mz, const float* __restrict__ Mh,
        const float* __restrict__ bz_eff, const float* __restrict__ bh_eff,
        const float* __restrict__ s_ptr,
        const float* __restrict__ W1, const float* __restrict__ b1,
        const float* __restrict__ W2, const float* __restrict__ b2,
        float* __restrict__ out) {
    __shared__ int   sEdge[EBLK];         // 16 KB
    __shared__ int   sOff[ABLK + 1];
    __shared__ float sAcc[ABLK * 32];     // 8 KB
    __shared__ float sMz[1024], sMh[1024], sW1[2048], sW2[6400];   // 42 KB
    __shared__ float sbz[32], sbh[32], sb1[64], sb2[100];
    int t = threadIdx.x;
    const int nodeBase = blockIdx.x * ABLK;

    sMz[t] = Mz[t]; sMh[t] = Mh[t];
    for (int j = t; j < 2048; j += 1024) sW1[j] = W1[j];
    for (int j = t; j < 6400; j += 1024) sW2[j] = W2[j];
    if (t < 32) { sbz[t] = bz_eff[t]; sbh[t] = bh_eff[t]; }
    if (t >= 32 && t < 96) sb1[t - 32] = b1[t - 32];
    if (t >= 128 && t < 228) sb2[t - 128] = b2[t - 128];
    if (t < ABLK) sOff[t] = row_start[nodeBase + t];
    if (t == ABLK) {
        int last = nodeBase + ABLK - 1;   // always inside one bucket (ABLK | 256)
        sOff[ABLK] = row_start[last] + deg[last];
    }
    __syncthreads();

    const int e_begin = sOff[0];
    const int cnt = sOff[ABLK] - e_begin;
    for (int j = t; j < cnt && j < EBLK; j += 1024) sEdge[j] = ebuf[e_begin + j];
    __syncthreads();

    const int w = t >> 6, lane = t & 63;
    const int g = lane >> 3, q = lane & 7;
    const float4* y4 = (const float4*)y;

    if (cnt <= EBLK) {
        // fast path: indices from LDS, predicated 4-deep gather (zero-row sink)
#pragma unroll
        for (int k = 0; k < 4; ++k) {
            int r = w * 4 + k;
            int i = nodeBase + r;
            if (i >= N_AGENT) break;      // wave-uniform
            int e0 = sOff[r] - e_begin, e1 = sOff[r + 1] - e_begin;
            float ax = 0.f, ay = 0.f, az = 0.f, aw = 0.f;
            for (int j = e0 + g; j < e1; j += 32) {
                int i0 = sEdge[j];
                int i1 = (j + 8  < e1) ? sEdge[j + 8]  : N_NODES;
                int i2 = (j + 16 < e1) ? sEdge[j + 16] : N_NODES;
                int i3 = (j + 24 < e1) ? sEdge[j + 24] : N_NODES;
                float4 v0 = y4[(size_t)i0 * 8 + q];
                float4 v1 = y4[(size_t)i1 * 8 + q];
                float4 v2 = y4[(size_t)i2 * 8 + q];
                float4 v3 = y4[(size_t)i3 * 8 + q];
                ax += (v0.x + v1.x) + (v2.x + v3.x);
                ay += (v0.y + v1.y) + (v2.y + v3.y);
                az += (v0.z + v1.z) + (v2.z + v3.z);
                aw += (v0.w + v1.w) + (v2.w + v3.w);
            }
#pragma unroll
            for (int off = 8; off <= 32; off <<= 1) {
                ax += __shfl_xor(ax, off, 64);
                ay += __shfl_xor(ay, off, 64);
                az += __shfl_xor(az, off, 64);
                aw += __shfl_xor(aw, off, 64);
            }
            if (g == 0)
                *(float4*)&sAcc[r * 32 + q * 4] = make_float4(ax, ay, az, aw);
        }
    } else {
        // fallback (statistically never): round-4 proven global-read loop
#pragma unroll
        for (int k = 0; k < 4; ++k) {
            int r = w * 4 + k;
            int i = nodeBase + r;
            if (i >= N_AGENT) break;
            int e0 = sOff[r], e1 = sOff[r + 1];
            float ax = 0.f, ay = 0.f, az = 0.f, aw = 0.f;
            int j = e0 + g;
            for (; j + 24 < e1; j += 32) {
                int s0 = ebuf[j];
                int s1 = ebuf[j + 8];
                int s2 = ebuf[j + 16];
                int s3 = ebuf[j + 24];
                float4 v0 = y4[(size_t)s0 * 8 + q];
                float4 v1 = y4[(size_t)s1 * 8 + q];
                float4 v2 = y4[(size_t)s2 * 8 + q];
                float4 v3 = y4[(size_t)s3 * 8 + q];
                ax += (v0.x + v1.x) + (v2.x + v3.x);
                ay += (v0.y + v1.y) + (v2.y + v3.y);
                az += (v0.z + v1.z) + (v2.z + v3.z);
                aw += (v0.w + v1.w) + (v2.w + v3.w);
            }
            for (; j < e1; j += 8) {
                int s0 = ebuf[j];
                float4 v0 = y4[(size_t)s0 * 8 + q];
                ax += v0.x; ay += v0.y; az += v0.z; aw += v0.w;
            }
#pragma unroll
            for (int off = 8; off <= 32; off <<= 1) {
                ax += __shfl_xor(ax, off, 64);
                ay += __shfl_xor(ay, off, 64);
                az += __shfl_xor(az, off, 64);
                aw += __shfl_xor(aw, off, 64);
            }
            if (g == 0)
                *(float4*)&sAcc[r * 32 + q * 4] = make_float4(ax, ay, az, aw);
        }
    }
    __syncthreads();

    // epilogue: 32 groups of 32 lanes, 2 rows each
    const float s = *s_ptr;
    const int c = t & 31, g2 = t >> 5;
    for (int r = g2; r < ABLK; r += 32) {
        int i = nodeBase + r;
        if (i >= N_AGENT) break;
        float di = rsqrtf((float)deg[i] + 1.0f);
        float a = (sAcc[r * 32 + c] + y[(size_t)i * HID + c]) * di;
        float uz = sbz[c], uh = sbh[c];
#pragma unroll
        for (int k = 0; k < 32; ++k) {
            float ak = __shfl(a, k, 32);
            uz += ak * sMz[k * 32 + c];
            uh += ak * sMh[k * 32 + c];
        }
        float z = 1.0f / (1.0f + expf(-uz));
        float h = s * (1.0f - z) * tanhf(uh);
        h = fmaxf(h, 0.0f);
        float t0 = sb1[c], t1 = sb1[c + 32];
#pragma unroll
        for (int k = 0; k < 32; ++k) {
            float hk = __shfl(h, k, 32);
            t0 += hk * sW1[k * 64 + c];
            t1 += hk * sW1[k * 64 + c + 32];
        }
        t0 = fmaxf(t0, 0.0f); t1 = fmaxf(t1, 0.0f);
        int j3 = (c < 4) ? (c + 96) : 99;
        float o0 = sb2[c];
        float o1 = sb2[c + 32];
        float o2 = sb2[c + 64];
        float o3 = sb2[j3];
#pragma unroll
        for (int k = 0; k < 32; ++k) {
            float ta = __shfl(t0, k, 32);
            float tb = __shfl(t1, k, 32);
            o0 += ta * sW2[k * 100 + c]      + tb * sW2[(k + 32) * 100 + c];
            o1 += ta * sW2[k * 100 + c + 32] + tb * sW2[(k + 32) * 100 + c + 32];
            o2 += ta * sW2[k * 100 + c + 64] + tb * sW2[(k + 32) * 100 + c + 64];
            o3 += ta * sW2[k * 100 + j3]     + tb * sW2[(k + 32) * 100 + j3];
        }
        float* orow = out + (size_t)i * 100;
        orow[c] = o0;
        orow[c + 32] = o1;
        orow[c + 64] = o2;
        if (c < 4) orow[c + 96] = o3;
    }
}

extern "C" void kernel_launch(void* const* d_in, const int* in_sizes, int n_in,
                              void* d_out, int out_size, void* d_ws, size_t ws_size,
                              hipStream_t stream) {
    const float* agent_x = (const float*)d_in[0];
    const float* map_x   = (const float*)d_in[1];
    const int*   ei      = (const int*)d_in[2];
    const float* W_agent = (const float*)d_in[3];
    const float* b_agent = (const float*)d_in[4];
    const float* W_map   = (const float*)d_in[5];
    const float* b_map   = (const float*)d_in[6];
    const float* Wz_c    = (const float*)d_in[7];
    const float* bz_c    = (const float*)d_in[8];
    const float* Wh_c    = (const float*)d_in[11];
    const float* bh_c    = (const float*)d_in[12];
    const float* Wz_l    = (const float*)d_in[13];
    const float* bz_l    = (const float*)d_in[14];
    const float* Wh_l    = (const float*)d_in[17];
    const float* bh_l    = (const float*)d_in[18];
    const float* attn    = (const float*)d_in[19];
    const float* W1      = (const float*)d_in[20];
    const float* b1      = (const float*)d_in[21];
    const float* W2      = (const float*)d_in[22];
    const float* b2      = (const float*)d_in[23];
    float* out = (float*)d_out;

    const int* e_src = ei;
    const int* e_dst = ei + NE;

    // workspace layout (float-element offsets); total ~29.5 MB
    float* ws       = (float*)d_ws;
    float* y        = ws;                          // (N_NODES+1)*HID = 3,200,032 (pad 3,200,256)
    float* Mz       = ws + 3200256;                // 1024
    float* Mh       = ws + 3201280;                // 1024
    float* bz       = ws + 3202304;                // 32
    float* bh       = ws + 3202336;                // 32
    float* sS       = ws + 3202368;                // 1 (pad to 3202560)
    int*   deg      = (int*)(ws + 3202560);        // 100,000 (pad to 3302656)
    int*   cursor   = (int*)(ws + 3302656);        // 391 (pad to 3303168)
    int*   row_start= (int*)(ws + 3303168);        // 60,160 -> 3363328
    int*   ebuf     = (int*)(ws + 3363328);        // NBUCK*CAP = 4,003,840 -> end 7,367,168

    k_precompute<<<1, 1024, 0, stream>>>(Wz_c, bz_c, Wh_c, bh_c, Wz_l, bz_l,
                                         Wh_l, bh_l, attn, Mz, Mh, bz, bh, sS, cursor);
    k_partition<<<(NE + TILE - 1) / TILE, PTHREADS, 0, stream>>>(e_src, e_dst, cursor, ebuf);
    k_hist<<<NBUCK, 256, 0, stream>>>(cursor, ebuf, deg);
    k_encode<<<((N_NODES + 1) * HID + 255) / 256, 256, 0, stream>>>(
        agent_x, map_x, W_agent, b_agent, W_map, b_map, deg, y);
    k_sortlocal<<<NABUCK, 1024, 0, stream>>>(cursor, ebuf, deg, row_start);
    k_aggmlp<<<(N_AGENT + ABLK - 1) / ABLK, 1024, 0, stream>>>(
        row_start, deg, ebuf, y, Mz, Mh, bz, bh, sS, W1, b1, W2, b2, out);
}

// Round 6
// 318.621 us; speedup vs baseline: 2.3414x; 1.0422x over previous
//
#include <hip/hip_runtime.h>
#include <math.h>

#define N_AGENT 60000
#define N_MAP   40000
#define N_NODES 100000
#define NE      3200000
#define HID     32
#define PERIODS 30

#define NBUCK   391        // ceil(100000/256) buckets of 256 dst nodes
#define NABUCK  235        // buckets containing agent dsts
#define CAP     10240      // per-bucket capacity (mean 8192, +22 sigma)
#define TILE    4096       // edges per partition block
#define PTHREADS 512
#define ABLK    128        // dsts per k_aggmlp block (one 8-lane group per dst)
#define EBLK    5120       // staged edges per block (mean 4096, sigma 64 -> +16 sigma)

// ---------------- kernel 0: fold weights, softmax sum, cursor init ----------------
__global__ void k_precompute(const float* Wz_c, const float* bz_c,
                             const float* Wh_c, const float* bh_c,
                             const float* Wz_l, const float* bz_l,
                             const float* Wh_l, const float* bh_l,
                             const float* attn,
                             float* Mz, float* Mh, float* bz_eff, float* bh_eff,
                             float* s_out, int* cursor) {
    int t = threadIdx.x;            // blockDim = 1024
    int k = t >> 5, c = t & 31;
    float mz = 0.f, mh = 0.f;
    for (int j = 0; j < HID; ++j) {
        mz += Wz_c[k * HID + j] * Wz_l[j * HID + c];   // Wz_l rows 0..31 (zeros half dead)
        mh += Wh_c[k * HID + j] * Wh_l[j * HID + c];
    }
    Mz[t] = mz; Mh[t] = mh;
    if (t < NBUCK) cursor[t] = t * CAP;
    if (t < HID) {
        float bz = bz_l[t], bh = bh_l[t];
        for (int j = 0; j < HID; ++j) {
            bz += bz_c[j] * Wz_l[j * HID + t];
            bh += bh_c[j] * Wh_l[j * HID + t];
        }
        bz_eff[t] = bz; bh_eff[t] = bh;
    }
    if (t == 0) {
        float m = -1e30f;
        for (int i = 0; i < PERIODS; ++i) m = fmaxf(m, attn[i]);
        float S = 0.f;
        for (int i = 0; i < PERIODS; ++i) S += expf(attn[i] - m);
        float s = 0.f;
        for (int i = 0; i < PERIODS; ++i) s += expf(attn[i] - m) / S;
        *s_out = s;
    }
}

// ---------------- kernel 1: LDS-staged multisplit partition (all edges) ----------------
// pack = src | (dst_low << 17); bucket = dst >> 8
// one-pass rank: first LDS atomic returns the local rank; int4-vectorized edge loads.
__global__ __launch_bounds__(PTHREADS) void k_partition(
        const int* __restrict__ src, const int* __restrict__ dst,
        int* __restrict__ cursor, int* __restrict__ ebuf) {
    __shared__ int sCnt[NBUCK];
    __shared__ int sBase[NBUCK + 1];
    __shared__ int sGbase[NBUCK];
    __shared__ int sScan[PTHREADS];
    __shared__ int sReorder[TILE];
    int t = threadIdx.x;
    int tileBase = blockIdx.x * TILE;
    int tcount = NE - tileBase; if (tcount > TILE) tcount = TILE;

    if (t < NBUCK) sCnt[t] = 0;
    __syncthreads();

    int pb[8], pp[8], pr[8];
    const int4* s4 = (const int4*)src;
    const int4* d4 = (const int4*)dst;
#pragma unroll
    for (int k = 0; k < 2; ++k) {
        int e4 = (tileBase >> 2) + t + k * PTHREADS;
        int valid = (e4 << 2) < NE;
        int4 sv, dv;
        if (valid) { sv = s4[e4]; dv = d4[e4]; }
#define PROC(m, SS, DD) { int kk = k * 4 + m;                                  \
        if (valid) { pb[kk] = (DD) >> 8;                                       \
                     pp[kk] = (SS) | (((DD) & 255) << 17);                     \
                     pr[kk] = atomicAdd(&sCnt[pb[kk]], 1); }                   \
        else pb[kk] = -1; }
        PROC(0, sv.x, dv.x)
        PROC(1, sv.y, dv.y)
        PROC(2, sv.z, dv.z)
        PROC(3, sv.w, dv.w)
#undef PROC
    }
    __syncthreads();

    // inclusive scan of sCnt via sScan (Hillis-Steele over 512 threads)
    int v = (t < NBUCK) ? sCnt[t] : 0;
    sScan[t] = v;
    __syncthreads();
    for (int s = 1; s < PTHREADS; s <<= 1) {
        int a = (t >= s) ? sScan[t - s] : 0;
        __syncthreads();
        sScan[t] += a;
        __syncthreads();
    }
    if (t <= NBUCK) sBase[t] = sScan[t] - v;   // exclusive; sBase[NBUCK] = tile total
    __syncthreads();
    // reserve global space
    if (t < NBUCK && sCnt[t] > 0) sGbase[t] = atomicAdd(&cursor[t], sCnt[t]);
    __syncthreads();
    // place by saved rank
#pragma unroll
    for (int k = 0; k < 8; ++k) {
        if (pb[k] >= 0) sReorder[sBase[pb[k]] + pr[k]] = pp[k];
    }
    __syncthreads();
    // coalesced flush: binary-search bucket owning slot j
#pragma unroll
    for (int k = 0; k < 8; ++k) {
        int j = t + k * PTHREADS;
        if (j < tcount) {
            int lo = 0, hi = NBUCK;
            while (hi - lo > 1) {
                int m = (lo + hi) >> 1;
                if (sBase[m] <= j) lo = m; else hi = m;
            }
            ebuf[sGbase[lo] + (j - sBase[lo])] = sReorder[j];
        }
    }
}

// ---------------- kernel 2: per-bucket degree histogram (LDS atomics only) ----------------
__global__ __launch_bounds__(256) void k_hist(const int* __restrict__ cursor,
                                              const int* __restrict__ ebuf,
                                              int* __restrict__ deg) {
    __shared__ int h[256];
    int t = threadIdx.x;
    int b = blockIdx.x;
    h[t] = 0;
    __syncthreads();
    int start = b * CAP;
    int cnt = cursor[b] - start;
    for (int j = t; j < cnt; j += 256)
        atomicAdd(&h[(ebuf[start + j] >> 17) & 255], 1);
    __syncthreads();
    int node = b * 256 + t;
    if (node < N_NODES) deg[node] = h[t];
}

// ---------------- kernel 3: node encoders, pre-scaled by dinv; zero row at N_NODES ------
__global__ void k_encode(const float* __restrict__ agent_x, const float* __restrict__ map_x,
                         const float* __restrict__ W_agent, const float* __restrict__ b_agent,
                         const float* __restrict__ W_map, const float* __restrict__ b_map,
                         const int* __restrict__ deg,
                         float* __restrict__ y) {
    int t = blockIdx.x * blockDim.x + threadIdx.x;
    if (t >= (N_NODES + 1) * HID) return;
    int i = t >> 5, c = t & 31;
    float acc = 0.f;
    if (i < N_AGENT) {
        float v = (c < 9) ? agent_x[(size_t)i * 9 + c] : 0.f;
        acc = b_agent[c];
#pragma unroll
        for (int k = 0; k < 9; ++k) acc += __shfl(v, k, 32) * W_agent[k * HID + c];
        acc *= rsqrtf((float)deg[i] + 1.0f);
    } else if (i < N_NODES) {
        float v = (c < 6) ? map_x[(size_t)(i - N_AGENT) * 6 + c] : 0.f;
        acc = b_map[c];
#pragma unroll
        for (int k = 0; k < 6; ++k) acc += __shfl(v, k, 32) * W_map[k * HID + c];
        acc *= rsqrtf((float)deg[i] + 1.0f);
    }
    y[t] = acc;                       // i == N_NODES -> zero row (gather sink)
}

// ---------------- kernel 4: per-bucket in-place CSR sort (agent buckets only) ----------
__global__ __launch_bounds__(1024) void k_sortlocal(
        const int* __restrict__ cursor, int* __restrict__ ebuf,
        const int* __restrict__ deg, int* __restrict__ row_start) {
    __shared__ int sSorted[CAP];          // 40 KB
    __shared__ int sBase[256];
    __shared__ int sCnt[256];
    __shared__ int sScan[256];
    int t = threadIdx.x;
    const int b = blockIdx.x;
    const int nodeBase = b * 256;

    int d0 = 0;
    if (t < 256) {
        d0 = deg[nodeBase + t];
        sCnt[t] = 0;
        sScan[t] = d0;
    }
    __syncthreads();
    for (int st = 1; st < 256; st <<= 1) {
        int a = 0;
        if (t < 256 && t >= st) a = sScan[t - st];
        __syncthreads();
        if (t < 256) sScan[t] += a;
        __syncthreads();
    }
    if (t < 256) {
        sBase[t] = sScan[t] - d0;
        row_start[nodeBase + t] = b * CAP + sBase[t];
    }
    __syncthreads();

    const int start = b * CAP;
    const int cnt = cursor[b] - start;
    for (int j = t; j < cnt; j += 1024) {
        int p = ebuf[start + j];
        int dl = (p >> 17) & 255;
        int r = atomicAdd(&sCnt[dl], 1);
        sSorted[sBase[dl] + r] = p & 0x1FFFF;
    }
    __syncthreads();
    for (int j = t; j < cnt; j += 1024)
        ebuf[start + j] = sSorted[j];      // in place: block owns this range
}

// ---------------- kernel 5: fused CSR gather + gates + MLP ----------------
// One 8-lane group per dst: the group serially accumulates all its dst's edges in
// 4 VGPRs (4-edge predicated unroll -> 4 independent 128B gathers in flight/group,
// 32/wave), holds the complete 32-float row -> NO cross-lane reduce, no vmcnt drain.
__global__ __launch_bounds__(1024) void k_aggmlp(
        const int* __restrict__ row_start, const int* __restrict__ deg,
        const int* __restrict__ ebuf, const float* __restrict__ y,
        const float* __restrict__ Mz, const float* __restrict__ Mh,
        const float* __restrict__ bz_eff, const float* __restrict__ bh_eff,
        const float* __restrict__ s_ptr,
        const float* __restrict__ W1, const float* __restrict__ b1,
        const float* __restrict__ W2, const float* __restrict__ b2,
        float* __restrict__ out) {
    __shared__ int   sEdge[EBLK];         // 20 KB
    __shared__ int   sOff[ABLK + 1];
    __shared__ float sAcc[ABLK * 32];     // 16 KB
    __shared__ float sMz[1024], sMh[1024], sW1[2048], sW2[6400];   // 42 KB
    __shared__ float sbz[32], sbh[32], sb1[64], sb2[100];
    int t = threadIdx.x;
    const int nodeBase = blockIdx.x * ABLK;

    sMz[t] = Mz[t]; sMh[t] = Mh[t];
    for (int j = t; j < 2048; j += 1024) sW1[j] = W1[j];
    for (int j = t; j < 6400; j += 1024) sW2[j] = W2[j];
    if (t < 32) { sbz[t] = bz_eff[t]; sbh[t] = bh_eff[t]; }
    if (t >= 32 && t < 96) sb1[t - 32] = b1[t - 32];
    if (t >= 128 && t < 228) sb2[t - 128] = b2[t - 128];
    if (t < ABLK) sOff[t] = row_start[nodeBase + t];
    if (t == ABLK) {
        int last = nodeBase + ABLK - 1;   // block always inside one bucket (128 | 256)
        sOff[ABLK] = row_start[last] + deg[last];
    }
    __syncthreads();

    const int e_begin = sOff[0];
    const int cnt = sOff[ABLK] - e_begin;
    for (int j = t; j < cnt && j < EBLK; j += 1024) sEdge[j] = ebuf[e_begin + j];
    __syncthreads();

    const int lane = t & 63;
    const int r = (t >> 6) * 8 + (lane >> 3);   // dst row 0..127, one per 8-lane group
    const int q = lane & 7;
    const int i = nodeBase + r;
    const float4* y4 = (const float4*)y;

    if (cnt <= EBLK) {
        // fast path: indices from LDS, predicated 4-edge unroll (zero-row sink)
        if (i < N_AGENT) {
            int e0 = sOff[r] - e_begin, e1 = sOff[r + 1] - e_begin;
            float ax = 0.f, ay = 0.f, az = 0.f, aw = 0.f;
            for (int j = e0; j < e1; j += 4) {
                int i0 = sEdge[j];
                int i1 = (j + 1 < e1) ? sEdge[j + 1] : N_NODES;
                int i2 = (j + 2 < e1) ? sEdge[j + 2] : N_NODES;
                int i3 = (j + 3 < e1) ? sEdge[j + 3] : N_NODES;
                float4 v0 = y4[(size_t)i0 * 8 + q];
                float4 v1 = y4[(size_t)i1 * 8 + q];
                float4 v2 = y4[(size_t)i2 * 8 + q];
                float4 v3 = y4[(size_t)i3 * 8 + q];
                ax += (v0.x + v1.x) + (v2.x + v3.x);
                ay += (v0.y + v1.y) + (v2.y + v3.y);
                az += (v0.z + v1.z) + (v2.z + v3.z);
                aw += (v0.w + v1.w) + (v2.w + v3.w);
            }
            *(float4*)&sAcc[r * 32 + q * 4] = make_float4(ax, ay, az, aw);
        }
    } else {
        // fallback (statistically never): same loop, indices straight from global
        if (i < N_AGENT) {
            int e0 = sOff[r], e1 = sOff[r + 1];
            float ax = 0.f, ay = 0.f, az = 0.f, aw = 0.f;
            for (int j = e0; j < e1; j += 4) {
                int i0 = ebuf[j];
                int i1 = (j + 1 < e1) ? ebuf[j + 1] : N_NODES;
                int i2 = (j + 2 < e1) ? ebuf[j + 2] : N_NODES;
                int i3 = (j + 3 < e1) ? ebuf[j + 3] : N_NODES;
                float4 v0 = y4[(size_t)i0 * 8 + q];
                float4 v1 = y4[(size_t)i1 * 8 + q];
                float4 v2 = y4[(size_t)i2 * 8 + q];
                float4 v3 = y4[(size_t)i3 * 8 + q];
                ax += (v0.x + v1.x) + (v2.x + v3.x);
                ay += (v0.y + v1.y) + (v2.y + v3.y);
                az += (v0.z + v1.z) + (v2.z + v3.z);
                aw += (v0.w + v1.w) + (v2.w + v3.w);
            }
            *(float4*)&sAcc[r * 32 + q * 4] = make_float4(ax, ay, az, aw);
        }
    }
    __syncthreads();

    // epilogue: 32 groups of 32 lanes, 4 rows each
    const float s = *s_ptr;
    const int c = t & 31, g2 = t >> 5;
    for (int rr = g2; rr < ABLK; rr += 32) {
        int ii = nodeBase + rr;
        if (ii >= N_AGENT) break;
        float di = rsqrtf((float)deg[ii] + 1.0f);
        float a = (sAcc[rr * 32 + c] + y[(size_t)ii * HID + c]) * di;
        float uz = sbz[c], uh = sbh[c];
#pragma unroll
        for (int k = 0; k < 32; ++k) {
            float ak = __shfl(a, k, 32);
            uz += ak * sMz[k * 32 + c];
            uh += ak * sMh[k * 32 + c];
        }
        float z = 1.0f / (1.0f + expf(-uz));
        float h = s * (1.0f - z) * tanhf(uh);
        h = fmaxf(h, 0.0f);
        float t0 = sb1[c], t1 = sb1[c + 32];
#pragma unroll
        for (int k = 0; k < 32; ++k) {
            float hk = __shfl(h, k, 32);
            t0 += hk * sW1[k * 64 + c];
            t1 += hk * sW1[k * 64 + c + 32];
        }
        t0 = fmaxf(t0, 0.0f); t1 = fmaxf(t1, 0.0f);
        int j3 = (c < 4) ? (c + 96) : 99;
        float o0 = sb2[c];
        float o1 = sb2[c + 32];
        float o2 = sb2[c + 64];
        float o3 = sb2[j3];
#pragma unroll
        for (int k = 0; k < 32; ++k) {
            float ta = __shfl(t0, k, 32);
            float tb = __shfl(t1, k, 32);
            o0 += ta * sW2[k * 100 + c]      + tb * sW2[(k + 32) * 100 + c];
            o1 += ta * sW2[k * 100 + c + 32] + tb * sW2[(k + 32) * 100 + c + 32];
            o2 += ta * sW2[k * 100 + c + 64] + tb * sW2[(k + 32) * 100 + c + 64];
            o3 += ta * sW2[k * 100 + j3]     + tb * sW2[(k + 32) * 100 + j3];
        }
        float* orow = out + (size_t)ii * 100;
        orow[c] = o0;
        orow[c + 32] = o1;
        orow[c + 64] = o2;
        if (c < 4) orow[c + 96] = o3;
    }
}

extern "C" void kernel_launch(void* const* d_in, const int* in_sizes, int n_in,
                              void* d_out, int out_size, void* d_ws, size_t ws_size,
                              hipStream_t stream) {
    const float* agent_x = (const float*)d_in[0];
    const float* map_x   = (const float*)d_in[1];
    const int*   ei      = (const int*)d_in[2];
    const float* W_agent = (const float*)d_in[3];
    const float* b_agent = (const float*)d_in[4];
    const float* W_map   = (const float*)d_in[5];
    const float* b_map   = (const float*)d_in[6];
    const float* Wz_c    = (const float*)d_in[7];
    const float* bz_c    = (const float*)d_in[8];
    const float* Wh_c    = (const float*)d_in[11];
    const float* bh_c    = (const float*)d_in[12];
    const float* Wz_l    = (const float*)d_in[13];
    const float* bz_l    = (const float*)d_in[14];
    const float* Wh_l    = (const float*)d_in[17];
    const float* bh_l    = (const float*)d_in[18];
    const float* attn    = (const float*)d_in[19];
    const float* W1      = (const float*)d_in[20];
    const float* b1      = (const float*)d_in[21];
    const float* W2      = (const float*)d_in[22];
    const float* b2      = (const float*)d_in[23];
    float* out = (float*)d_out;

    const int* e_src = ei;
    const int* e_dst = ei + NE;

    // workspace layout (float-element offsets); total ~29.5 MB
    float* ws       = (float*)d_ws;
    float* y        = ws;                          // (N_NODES+1)*HID = 3,200,032 (pad 3,200,256)
    float* Mz       = ws + 3200256;                // 1024
    float* Mh       = ws + 3201280;                // 1024
    float* bz       = ws + 3202304;                // 32
    float* bh       = ws + 3202336;                // 32
    float* sS       = ws + 3202368;                // 1 (pad to 3202560)
    int*   deg      = (int*)(ws + 3202560);        // 100,000 (pad to 3302656)
    int*   cursor   = (int*)(ws + 3302656);        // 391 (pad to 3303168)
    int*   row_start= (int*)(ws + 3303168);        // 60,160 -> 3363328
    int*   ebuf     = (int*)(ws + 3363328);        // NBUCK*CAP = 4,003,840 -> end 7,367,168

    k_precompute<<<1, 1024, 0, stream>>>(Wz_c, bz_c, Wh_c, bh_c, Wz_l, bz_l,
                                         Wh_l, bh_l, attn, Mz, Mh, bz, bh, sS, cursor);
    k_partition<<<(NE + TILE - 1) / TILE, PTHREADS, 0, stream>>>(e_src, e_dst, cursor, ebuf);
    k_hist<<<NBUCK, 256, 0, stream>>>(cursor, ebuf, deg);
    k_encode<<<((N_NODES + 1) * HID + 255) / 256, 256, 0, stream>>>(
        agent_x, map_x, W_agent, b_agent, W_map, b_map, deg, y);
    k_sortlocal<<<NABUCK, 1024, 0, stream>>>(cursor, ebuf, deg, row_start);
    k_aggmlp<<<(N_AGENT + ABLK - 1) / ABLK, 1024, 0, stream>>>(
        row_start, deg, ebuf, y, Mz, Mh, bz, bh, sS, W1, b1, W2, b2, out);
}

// Round 7
// 315.347 us; speedup vs baseline: 2.3657x; 1.0104x over previous
//
#include <hip/hip_runtime.h>
#include <math.h>

#define N_AGENT 60000
#define N_MAP   40000
#define N_NODES 100000
#define NE      3200000
#define HID     32
#define PERIODS 30

#define NBUCK   391        // ceil(100000/256) buckets of 256 dst nodes
#define NABUCK  235        // buckets containing agent dsts
#define CAP     10240      // per-bucket capacity (mean 8192, +22 sigma)
#define TILE    4096       // edges per partition block
#define PTHREADS 512
#define ABLK    128        // dsts per k_aggmlp block (one 8-lane group per dst)

// phase-shared LDS buffer (floats). Phase A: edge indices (int). Phase B: weights.
#define BUFSZ   10724
#define OF_MZ   0
#define OF_MH   1024
#define OF_W1   2048
#define OF_W2   4096
#define OF_BZ   10496
#define OF_BH   10528
#define OF_B1   10560
#define OF_B2   10624

// ---------------- kernel 0: fold weights, softmax sum, cursor init ----------------
__global__ void k_precompute(const float* Wz_c, const float* bz_c,
                             const float* Wh_c, const float* bh_c,
                             const float* Wz_l, const float* bz_l,
                             const float* Wh_l, const float* bh_l,
                             const float* attn,
                             float* Mz, float* Mh, float* bz_eff, float* bh_eff,
                             float* s_out, int* cursor) {
    int t = threadIdx.x;            // blockDim = 1024
    int k = t >> 5, c = t & 31;
    float mz = 0.f, mh = 0.f;
    for (int j = 0; j < HID; ++j) {
        mz += Wz_c[k * HID + j] * Wz_l[j * HID + c];   // Wz_l rows 0..31 (zeros half dead)
        mh += Wh_c[k * HID + j] * Wh_l[j * HID + c];
    }
    Mz[t] = mz; Mh[t] = mh;
    if (t < NBUCK) cursor[t] = t * CAP;
    if (t < HID) {
        float bz = bz_l[t], bh = bh_l[t];
        for (int j = 0; j < HID; ++j) {
            bz += bz_c[j] * Wz_l[j * HID + t];
            bh += bh_c[j] * Wh_l[j * HID + t];
        }
        bz_eff[t] = bz; bh_eff[t] = bh;
    }
    if (t == 0) {
        float m = -1e30f;
        for (int i = 0; i < PERIODS; ++i) m = fmaxf(m, attn[i]);
        float S = 0.f;
        for (int i = 0; i < PERIODS; ++i) S += expf(attn[i] - m);
        float s = 0.f;
        for (int i = 0; i < PERIODS; ++i) s += expf(attn[i] - m) / S;
        *s_out = s;
    }
}

// ---------------- kernel 1: LDS-staged multisplit partition (all edges) ----------------
// pack = src | (dst_low << 17); bucket = dst >> 8
// one-pass rank: first LDS atomic returns the local rank; int4-vectorized edge loads.
__global__ __launch_bounds__(PTHREADS) void k_partition(
        const int* __restrict__ src, const int* __restrict__ dst,
        int* __restrict__ cursor, int* __restrict__ ebuf) {
    __shared__ int sCnt[NBUCK];
    __shared__ int sBase[NBUCK + 1];
    __shared__ int sGbase[NBUCK];
    __shared__ int sScan[PTHREADS];
    __shared__ int sReorder[TILE];
    int t = threadIdx.x;
    int tileBase = blockIdx.x * TILE;
    int tcount = NE - tileBase; if (tcount > TILE) tcount = TILE;

    if (t < NBUCK) sCnt[t] = 0;
    __syncthreads();

    int pb[8], pp[8], pr[8];
    const int4* s4 = (const int4*)src;
    const int4* d4 = (const int4*)dst;
#pragma unroll
    for (int k = 0; k < 2; ++k) {
        int e4 = (tileBase >> 2) + t + k * PTHREADS;
        int valid = (e4 << 2) < NE;
        int4 sv, dv;
        if (valid) { sv = s4[e4]; dv = d4[e4]; }
#define PROC(m, SS, DD) { int kk = k * 4 + m;                                  \
        if (valid) { pb[kk] = (DD) >> 8;                                       \
                     pp[kk] = (SS) | (((DD) & 255) << 17);                     \
                     pr[kk] = atomicAdd(&sCnt[pb[kk]], 1); }                   \
        else pb[kk] = -1; }
        PROC(0, sv.x, dv.x)
        PROC(1, sv.y, dv.y)
        PROC(2, sv.z, dv.z)
        PROC(3, sv.w, dv.w)
#undef PROC
    }
    __syncthreads();

    // inclusive scan of sCnt via sScan (Hillis-Steele over 512 threads)
    int v = (t < NBUCK) ? sCnt[t] : 0;
    sScan[t] = v;
    __syncthreads();
    for (int s = 1; s < PTHREADS; s <<= 1) {
        int a = (t >= s) ? sScan[t - s] : 0;
        __syncthreads();
        sScan[t] += a;
        __syncthreads();
    }
    if (t <= NBUCK) sBase[t] = sScan[t] - v;   // exclusive; sBase[NBUCK] = tile total
    __syncthreads();
    // reserve global space
    if (t < NBUCK && sCnt[t] > 0) sGbase[t] = atomicAdd(&cursor[t], sCnt[t]);
    __syncthreads();
    // place by saved rank
#pragma unroll
    for (int k = 0; k < 8; ++k) {
        if (pb[k] >= 0) sReorder[sBase[pb[k]] + pr[k]] = pp[k];
    }
    __syncthreads();
    // coalesced flush: binary-search bucket owning slot j
#pragma unroll
    for (int k = 0; k < 8; ++k) {
        int j = t + k * PTHREADS;
        if (j < tcount) {
            int lo = 0, hi = NBUCK;
            while (hi - lo > 1) {
                int m = (lo + hi) >> 1;
                if (sBase[m] <= j) lo = m; else hi = m;
            }
            ebuf[sGbase[lo] + (j - sBase[lo])] = sReorder[j];
        }
    }
}

// ---------------- kernel 2: per-bucket degree histogram (LDS atomics only) ----------------
__global__ __launch_bounds__(256) void k_hist(const int* __restrict__ cursor,
                                              const int* __restrict__ ebuf,
                                              int* __restrict__ deg) {
    __shared__ int h[256];
    int t = threadIdx.x;
    int b = blockIdx.x;
    h[t] = 0;
    __syncthreads();
    int start = b * CAP;
    int cnt = cursor[b] - start;
    for (int j = t; j < cnt; j += 256)
        atomicAdd(&h[(ebuf[start + j] >> 17) & 255], 1);
    __syncthreads();
    int node = b * 256 + t;
    if (node < N_NODES) deg[node] = h[t];
}

// ---------------- kernel 3: node encoders, pre-scaled by dinv; zero row at N_NODES ------
__global__ void k_encode(const float* __restrict__ agent_x, const float* __restrict__ map_x,
                         const float* __restrict__ W_agent, const float* __restrict__ b_agent,
                         const float* __restrict__ W_map, const float* __restrict__ b_map,
                         const int* __restrict__ deg,
                         float* __restrict__ y) {
    int t = blockIdx.x * blockDim.x + threadIdx.x;
    if (t >= (N_NODES + 1) * HID) return;
    int i = t >> 5, c = t & 31;
    float acc = 0.f;
    if (i < N_AGENT) {
        float v = (c < 9) ? agent_x[(size_t)i * 9 + c] : 0.f;
        acc = b_agent[c];
#pragma unroll
        for (int k = 0; k < 9; ++k) acc += __shfl(v, k, 32) * W_agent[k * HID + c];
        acc *= rsqrtf((float)deg[i] + 1.0f);
    } else if (i < N_NODES) {
        float v = (c < 6) ? map_x[(size_t)(i - N_AGENT) * 6 + c] : 0.f;
        acc = b_map[c];
#pragma unroll
        for (int k = 0; k < 6; ++k) acc += __shfl(v, k, 32) * W_map[k * HID + c];
        acc *= rsqrtf((float)deg[i] + 1.0f);
    }
    y[t] = acc;                       // i == N_NODES -> zero row (gather sink)
}

// ---------------- kernel 4: per-bucket in-place CSR sort (agent buckets only) ----------
__global__ __launch_bounds__(1024) void k_sortlocal(
        const int* __restrict__ cursor, int* __restrict__ ebuf,
        const int* __restrict__ deg, int* __restrict__ row_start) {
    __shared__ int sSorted[CAP];          // 40 KB
    __shared__ int sBase[256];
    __shared__ int sCnt[256];
    __shared__ int sScan[256];
    int t = threadIdx.x;
    const int b = blockIdx.x;
    const int nodeBase = b * 256;

    int d0 = 0;
    if (t < 256) {
        d0 = deg[nodeBase + t];
        sCnt[t] = 0;
        sScan[t] = d0;
    }
    __syncthreads();
    for (int st = 1; st < 256; st <<= 1) {
        int a = 0;
        if (t < 256 && t >= st) a = sScan[t - st];
        __syncthreads();
        if (t < 256) sScan[t] += a;
        __syncthreads();
    }
    if (t < 256) {
        sBase[t] = sScan[t] - d0;
        row_start[nodeBase + t] = b * CAP + sBase[t];
    }
    __syncthreads();

    const int start = b * CAP;
    const int cnt = cursor[b] - start;
    for (int j = t; j < cnt; j += 1024) {
        int p = ebuf[start + j];
        int dl = (p >> 17) & 255;
        int r = atomicAdd(&sCnt[dl], 1);
        sSorted[sBase[dl] + r] = p & 0x1FFFF;
    }
    __syncthreads();
    for (int j = t; j < cnt; j += 1024)
        ebuf[start + j] = sSorted[j];      // in place: block owns this range
}

// ---------------- kernel 5: fused CSR gather + gates + MLP (phase-shared LDS) ----------
// One 8-lane group per dst; 4-edge predicated unroll (4 x 128B gathers in flight/group).
// LDS 59.8 KB -> 2 blocks/CU (32 waves). sBuf holds edge indices during the gather
// phase, then is overwritten with the epilogue weights after the barrier.
__global__ __launch_bounds__(1024) void k_aggmlp(
        const int* __restrict__ row_start, const int* __restrict__ deg,
        const int* __restrict__ ebuf, const float* __restrict__ y,
        const float* __restrict__ Mz, const float* __restrict__ Mh,
        const float* __restrict__ bz_eff, const float* __restrict__ bh_eff,
        const float* __restrict__ s_ptr,
        const float* __restrict__ W1, const float* __restrict__ b1,
        const float* __restrict__ W2, const float* __restrict__ b2,
        float* __restrict__ out) {
    __shared__ float sBuf[BUFSZ];         // 42.9 KB, phase-shared
    __shared__ float sAcc[ABLK * 32];     // 16 KB
    __shared__ int   sOff[ABLK + 1];
    int t = threadIdx.x;
    const int nodeBase = blockIdx.x * ABLK;

    if (t < ABLK) sOff[t] = row_start[nodeBase + t];
    if (t == ABLK) {
        int last = nodeBase + ABLK - 1;   // block always inside one bucket (128 | 256)
        sOff[ABLK] = row_start[last] + deg[last];
    }
    __syncthreads();

    // phase A: stage this block's edge indices (cnt <= CAP = 10240 <= BUFSZ)
    int* sEdge = (int*)sBuf;
    const int e_begin = sOff[0];
    const int cnt = sOff[ABLK] - e_begin;
    for (int j = t; j < cnt; j += 1024) sEdge[j] = ebuf[e_begin + j];
    __syncthreads();

    const int lane = t & 63;
    const int r = (t >> 6) * 8 + (lane >> 3);   // dst row 0..127, one per 8-lane group
    const int q = lane & 7;
    const int i = nodeBase + r;
    const float4* y4 = (const float4*)y;

    if (i < N_AGENT) {
        int e0 = sOff[r] - e_begin, e1 = sOff[r + 1] - e_begin;
        float ax = 0.f, ay = 0.f, az = 0.f, aw = 0.f;
        for (int j = e0; j < e1; j += 4) {
            int i0 = sEdge[j];
            int i1 = (j + 1 < e1) ? sEdge[j + 1] : N_NODES;
            int i2 = (j + 2 < e1) ? sEdge[j + 2] : N_NODES;
            int i3 = (j + 3 < e1) ? sEdge[j + 3] : N_NODES;
            float4 v0 = y4[(size_t)i0 * 8 + q];
            float4 v1 = y4[(size_t)i1 * 8 + q];
            float4 v2 = y4[(size_t)i2 * 8 + q];
            float4 v3 = y4[(size_t)i3 * 8 + q];
            ax += (v0.x + v1.x) + (v2.x + v3.x);
            ay += (v0.y + v1.y) + (v2.y + v3.y);
            az += (v0.z + v1.z) + (v2.z + v3.z);
            aw += (v0.w + v1.w) + (v2.w + v3.w);
        }
        *(float4*)&sAcc[r * 32 + q * 4] = make_float4(ax, ay, az, aw);
    }
    __syncthreads();

    // phase B: overwrite sBuf with epilogue weights (L2-hot, ~11 loads/thread)
    sBuf[OF_MZ + t] = Mz[t];
    sBuf[OF_MH + t] = Mh[t];
    for (int j = t; j < 2048; j += 1024) sBuf[OF_W1 + j] = W1[j];
    for (int j = t; j < 6400; j += 1024) sBuf[OF_W2 + j] = W2[j];
    if (t < 32) { sBuf[OF_BZ + t] = bz_eff[t]; sBuf[OF_BH + t] = bh_eff[t]; }
    if (t >= 64 && t < 128) sBuf[OF_B1 + t - 64] = b1[t - 64];
    if (t >= 128 && t < 228) sBuf[OF_B2 + t - 128] = b2[t - 128];
    __syncthreads();

    // epilogue: 32 groups of 32 lanes, 4 rows each
    const float s = *s_ptr;
    const int c = t & 31, g2 = t >> 5;
    for (int rr = g2; rr < ABLK; rr += 32) {
        int ii = nodeBase + rr;
        if (ii >= N_AGENT) break;
        float di = rsqrtf((float)deg[ii] + 1.0f);
        float a = (sAcc[rr * 32 + c] + y[(size_t)ii * HID + c]) * di;
        float uz = sBuf[OF_BZ + c], uh = sBuf[OF_BH + c];
#pragma unroll
        for (int k = 0; k < 32; ++k) {
            float ak = __shfl(a, k, 32);
            uz += ak * sBuf[OF_MZ + k * 32 + c];
            uh += ak * sBuf[OF_MH + k * 32 + c];
        }
        float z = 1.0f / (1.0f + expf(-uz));
        float h = s * (1.0f - z) * tanhf(uh);
        h = fmaxf(h, 0.0f);
        float t0 = sBuf[OF_B1 + c], t1 = sBuf[OF_B1 + c + 32];
#pragma unroll
        for (int k = 0; k < 32; ++k) {
            float hk = __shfl(h, k, 32);
            t0 += hk * sBuf[OF_W1 + k * 64 + c];
            t1 += hk * sBuf[OF_W1 + k * 64 + c + 32];
        }
        t0 = fmaxf(t0, 0.0f); t1 = fmaxf(t1, 0.0f);
        int j3 = (c < 4) ? (c + 96) : 99;
        float o0 = sBuf[OF_B2 + c];
        float o1 = sBuf[OF_B2 + c + 32];
        float o2 = sBuf[OF_B2 + c + 64];
        float o3 = sBuf[OF_B2 + j3];
#pragma unroll
        for (int k = 0; k < 32; ++k) {
            float ta = __shfl(t0, k, 32);
            float tb = __shfl(t1, k, 32);
            o0 += ta * sBuf[OF_W2 + k * 100 + c]      + tb * sBuf[OF_W2 + (k + 32) * 100 + c];
            o1 += ta * sBuf[OF_W2 + k * 100 + c + 32] + tb * sBuf[OF_W2 + (k + 32) * 100 + c + 32];
            o2 += ta * sBuf[OF_W2 + k * 100 + c + 64] + tb * sBuf[OF_W2 + (k + 32) * 100 + c + 64];
            o3 += ta * sBuf[OF_W2 + k * 100 + j3]     + tb * sBuf[OF_W2 + (k + 32) * 100 + j3];
        }
        float* orow = out + (size_t)ii * 100;
        orow[c] = o0;
        orow[c + 32] = o1;
        orow[c + 64] = o2;
        if (c < 4) orow[c + 96] = o3;
    }
}

extern "C" void kernel_launch(void* const* d_in, const int* in_sizes, int n_in,
                              void* d_out, int out_size, void* d_ws, size_t ws_size,
                              hipStream_t stream) {
    const float* agent_x = (const float*)d_in[0];
    const float* map_x   = (const float*)d_in[1];
    const int*   ei      = (const int*)d_in[2];
    const float* W_agent = (const float*)d_in[3];
    const float* b_agent = (const float*)d_in[4];
    const float* W_map   = (const float*)d_in[5];
    const float* b_map   = (const float*)d_in[6];
    const float* Wz_c    = (const float*)d_in[7];
    const float* bz_c    = (const float*)d_in[8];
    const float* Wh_c    = (const float*)d_in[11];
    const float* bh_c    = (const float*)d_in[12];
    const float* Wz_l    = (const float*)d_in[13];
    const float* bz_l    = (const float*)d_in[14];
    const float* Wh_l    = (const float*)d_in[17];
    const float* bh_l    = (const float*)d_in[18];
    const float* attn    = (const float*)d_in[19];
    const float* W1      = (const float*)d_in[20];
    const float* b1      = (const float*)d_in[21];
    const float* W2      = (const float*)d_in[22];
    const float* b2      = (const float*)d_in[23];
    float* out = (float*)d_out;

    const int* e_src = ei;
    const int* e_dst = ei + NE;

    // workspace layout (float-element offsets); total ~29.5 MB
    float* ws       = (float*)d_ws;
    float* y        = ws;                          // (N_NODES+1)*HID = 3,200,032 (pad 3,200,256)
    float* Mz       = ws + 3200256;                // 1024
    float* Mh       = ws + 3201280;                // 1024
    float* bz       = ws + 3202304;                // 32
    float* bh       = ws + 3202336;                // 32
    float* sS       = ws + 3202368;                // 1 (pad to 3202560)
    int*   deg      = (int*)(ws + 3202560);        // 100,000 (pad to 3302656)
    int*   cursor   = (int*)(ws + 3302656);        // 391 (pad to 3303168)
    int*   row_start= (int*)(ws + 3303168);        // 60,160 -> 3363328
    int*   ebuf     = (int*)(ws + 3363328);        // NBUCK*CAP = 4,003,840 -> end 7,367,168

    k_precompute<<<1, 1024, 0, stream>>>(Wz_c, bz_c, Wh_c, bh_c, Wz_l, bz_l,
                                         Wh_l, bh_l, attn, Mz, Mh, bz, bh, sS, cursor);
    k_partition<<<(NE + TILE - 1) / TILE, PTHREADS, 0, stream>>>(e_src, e_dst, cursor, ebuf);
    k_hist<<<NBUCK, 256, 0, stream>>>(cursor, ebuf, deg);
    k_encode<<<((N_NODES + 1) * HID + 255) / 256, 256, 0, stream>>>(
        agent_x, map_x, W_agent, b_agent, W_map, b_map, deg, y);
    k_sortlocal<<<NABUCK, 1024, 0, stream>>>(cursor, ebuf, deg, row_start);
    k_aggmlp<<<(N_AGENT + ABLK - 1) / ABLK, 1024, 0, stream>>>(
        row_start, deg, ebuf, y, Mz, Mh, bz, bh, sS, W1, b1, W2, b2, out);
}

// Round 8
// 304.860 us; speedup vs baseline: 2.4471x; 1.0344x over previous
//
#include <hip/hip_runtime.h>
#include <hip/hip_fp16.h>
#include <math.h>

#define N_AGENT 60000
#define N_MAP   40000
#define N_NODES 100000
#define NE      3200000
#define HID     32
#define PERIODS 30

#define NBUCK   391        // ceil(100000/256) buckets of 256 dst nodes
#define NABUCK  235        // buckets containing agent dsts
#define CAP     10240      // per-bucket capacity (mean 8192, +22 sigma)
#define TILE    4096       // edges per partition block
#define PTHREADS 512
#define ABLK    128        // dsts per k_aggmlp block (one 8-lane group per dst)

// phase-shared LDS buffer (floats). Phase A: edge indices (int). Phase B: weights.
#define BUFSZ   10724
#define OF_MZ   0
#define OF_MH   1024
#define OF_W1   2048
#define OF_W2   4096
#define OF_BZ   10496
#define OF_BH   10528
#define OF_B1   10560
#define OF_B2   10624

// ---------------- kernel 0: fold weights, softmax sum, cursor init ----------------
__global__ void k_precompute(const float* Wz_c, const float* bz_c,
                             const float* Wh_c, const float* bh_c,
                             const float* Wz_l, const float* bz_l,
                             const float* Wh_l, const float* bh_l,
                             const float* attn,
                             float* Mz, float* Mh, float* bz_eff, float* bh_eff,
                             float* s_out, int* cursor) {
    int t = threadIdx.x;            // blockDim = 1024
    int k = t >> 5, c = t & 31;
    float mz = 0.f, mh = 0.f;
    for (int j = 0; j < HID; ++j) {
        mz += Wz_c[k * HID + j] * Wz_l[j * HID + c];   // Wz_l rows 0..31 (zeros half dead)
        mh += Wh_c[k * HID + j] * Wh_l[j * HID + c];
    }
    Mz[t] = mz; Mh[t] = mh;
    if (t < NBUCK) cursor[t] = t * CAP;
    if (t < HID) {
        float bz = bz_l[t], bh = bh_l[t];
        for (int j = 0; j < HID; ++j) {
            bz += bz_c[j] * Wz_l[j * HID + t];
            bh += bh_c[j] * Wh_l[j * HID + t];
        }
        bz_eff[t] = bz; bh_eff[t] = bh;
    }
    if (t == 0) {
        float m = -1e30f;
        for (int i = 0; i < PERIODS; ++i) m = fmaxf(m, attn[i]);
        float S = 0.f;
        for (int i = 0; i < PERIODS; ++i) S += expf(attn[i] - m);
        float s = 0.f;
        for (int i = 0; i < PERIODS; ++i) s += expf(attn[i] - m) / S;
        *s_out = s;
    }
}

// ---------------- kernel 1: LDS-staged multisplit partition (all edges) ----------------
// pack = src | (dst_low << 17); bucket = dst >> 8
// one-pass rank: first LDS atomic returns the local rank; int4-vectorized edge loads.
__global__ __launch_bounds__(PTHREADS) void k_partition(
        const int* __restrict__ src, const int* __restrict__ dst,
        int* __restrict__ cursor, int* __restrict__ ebuf) {
    __shared__ int sCnt[NBUCK];
    __shared__ int sBase[NBUCK + 1];
    __shared__ int sGbase[NBUCK];
    __shared__ int sScan[PTHREADS];
    __shared__ int sReorder[TILE];
    int t = threadIdx.x;
    int tileBase = blockIdx.x * TILE;
    int tcount = NE - tileBase; if (tcount > TILE) tcount = TILE;

    if (t < NBUCK) sCnt[t] = 0;
    __syncthreads();

    int pb[8], pp[8], pr[8];
    const int4* s4 = (const int4*)src;
    const int4* d4 = (const int4*)dst;
#pragma unroll
    for (int k = 0; k < 2; ++k) {
        int e4 = (tileBase >> 2) + t + k * PTHREADS;
        int valid = (e4 << 2) < NE;
        int4 sv, dv;
        if (valid) { sv = s4[e4]; dv = d4[e4]; }
#define PROC(m, SS, DD) { int kk = k * 4 + m;                                  \
        if (valid) { pb[kk] = (DD) >> 8;                                       \
                     pp[kk] = (SS) | (((DD) & 255) << 17);                     \
                     pr[kk] = atomicAdd(&sCnt[pb[kk]], 1); }                   \
        else pb[kk] = -1; }
        PROC(0, sv.x, dv.x)
        PROC(1, sv.y, dv.y)
        PROC(2, sv.z, dv.z)
        PROC(3, sv.w, dv.w)
#undef PROC
    }
    __syncthreads();

    // inclusive scan of sCnt via sScan (Hillis-Steele over 512 threads)
    int v = (t < NBUCK) ? sCnt[t] : 0;
    sScan[t] = v;
    __syncthreads();
    for (int s = 1; s < PTHREADS; s <<= 1) {
        int a = (t >= s) ? sScan[t - s] : 0;
        __syncthreads();
        sScan[t] += a;
        __syncthreads();
    }
    if (t <= NBUCK) sBase[t] = sScan[t] - v;   // exclusive; sBase[NBUCK] = tile total
    __syncthreads();
    // reserve global space
    if (t < NBUCK && sCnt[t] > 0) sGbase[t] = atomicAdd(&cursor[t], sCnt[t]);
    __syncthreads();
    // place by saved rank
#pragma unroll
    for (int k = 0; k < 8; ++k) {
        if (pb[k] >= 0) sReorder[sBase[pb[k]] + pr[k]] = pp[k];
    }
    __syncthreads();
    // coalesced flush: binary-search bucket owning slot j
#pragma unroll
    for (int k = 0; k < 8; ++k) {
        int j = t + k * PTHREADS;
        if (j < tcount) {
            int lo = 0, hi = NBUCK;
            while (hi - lo > 1) {
                int m = (lo + hi) >> 1;
                if (sBase[m] <= j) lo = m; else hi = m;
            }
            ebuf[sGbase[lo] + (j - sBase[lo])] = sReorder[j];
        }
    }
}

// ---------------- kernel 2: per-bucket degree histogram (LDS atomics only) ----------------
__global__ __launch_bounds__(256) void k_hist(const int* __restrict__ cursor,
                                              const int* __restrict__ ebuf,
                                              int* __restrict__ deg) {
    __shared__ int h[256];
    int t = threadIdx.x;
    int b = blockIdx.x;
    h[t] = 0;
    __syncthreads();
    int start = b * CAP;
    int cnt = cursor[b] - start;
    for (int j = t; j < cnt; j += 256)
        atomicAdd(&h[(ebuf[start + j] >> 17) & 255], 1);
    __syncthreads();
    int node = b * 256 + t;
    if (node < N_NODES) deg[node] = h[t];
}

// ---------------- kernel 3: node encoders -> fp16 y, pre-scaled by dinv; zero row -------
__global__ void k_encode(const float* __restrict__ agent_x, const float* __restrict__ map_x,
                         const float* __restrict__ W_agent, const float* __restrict__ b_agent,
                         const float* __restrict__ W_map, const float* __restrict__ b_map,
                         const int* __restrict__ deg,
                         __half* __restrict__ y_h) {
    int t = blockIdx.x * blockDim.x + threadIdx.x;
    if (t >= (N_NODES + 1) * HID) return;
    int i = t >> 5, c = t & 31;
    float acc = 0.f;
    if (i < N_AGENT) {
        float v = (c < 9) ? agent_x[(size_t)i * 9 + c] : 0.f;
        acc = b_agent[c];
#pragma unroll
        for (int k = 0; k < 9; ++k) acc += __shfl(v, k, 32) * W_agent[k * HID + c];
        acc *= rsqrtf((float)deg[i] + 1.0f);
    } else if (i < N_NODES) {
        float v = (c < 6) ? map_x[(size_t)(i - N_AGENT) * 6 + c] : 0.f;
        acc = b_map[c];
#pragma unroll
        for (int k = 0; k < 6; ++k) acc += __shfl(v, k, 32) * W_map[k * HID + c];
        acc *= rsqrtf((float)deg[i] + 1.0f);
    }
    y_h[t] = __float2half(acc);       // i == N_NODES -> zero row (gather sink)
}

// ---------------- kernel 4: per-bucket in-place CSR sort (agent buckets only) ----------
__global__ __launch_bounds__(1024) void k_sortlocal(
        const int* __restrict__ cursor, int* __restrict__ ebuf,
        const int* __restrict__ deg, int* __restrict__ row_start) {
    __shared__ int sSorted[CAP];          // 40 KB
    __shared__ int sBase[256];
    __shared__ int sCnt[256];
    __shared__ int sScan[256];
    int t = threadIdx.x;
    const int b = blockIdx.x;
    const int nodeBase = b * 256;

    int d0 = 0;
    if (t < 256) {
        d0 = deg[nodeBase + t];
        sCnt[t] = 0;
        sScan[t] = d0;
    }
    __syncthreads();
    for (int st = 1; st < 256; st <<= 1) {
        int a = 0;
        if (t < 256 && t >= st) a = sScan[t - st];
        __syncthreads();
        if (t < 256) sScan[t] += a;
        __syncthreads();
    }
    if (t < 256) {
        sBase[t] = sScan[t] - d0;
        row_start[nodeBase + t] = b * CAP + sBase[t];
    }
    __syncthreads();

    const int start = b * CAP;
    const int cnt = cursor[b] - start;
    for (int j = t; j < cnt; j += 1024) {
        int p = ebuf[start + j];
        int dl = (p >> 17) & 255;
        int r = atomicAdd(&sCnt[dl], 1);
        sSorted[sBase[dl] + r] = p & 0x1FFFF;
    }
    __syncthreads();
    for (int j = t; j < cnt; j += 1024)
        ebuf[start + j] = sSorted[j];      // in place: block owns this range
}

// ---------------- kernel 5: fused CSR gather (fp16) + gates + MLP ----------------
// One 8-lane group per dst; fp16 rows = 64 B -> 8 B/lane (uint2). 8-edge predicated
// unroll -> 8 independent line-gathers in flight per group (64/wave). fp32 accum.
__global__ __launch_bounds__(1024) void k_aggmlp(
        const int* __restrict__ row_start, const int* __restrict__ deg,
        const int* __restrict__ ebuf, const __half* __restrict__ y_h,
        const float* __restrict__ Mz, const float* __restrict__ Mh,
        const float* __restrict__ bz_eff, const float* __restrict__ bh_eff,
        const float* __restrict__ s_ptr,
        const float* __restrict__ W1, const float* __restrict__ b1,
        const float* __restrict__ W2, const float* __restrict__ b2,
        float* __restrict__ out) {
    __shared__ float sBuf[BUFSZ];         // 42.9 KB, phase-shared
    __shared__ float sAcc[ABLK * 32];     // 16 KB
    __shared__ int   sOff[ABLK + 1];
    int t = threadIdx.x;
    const int nodeBase = blockIdx.x * ABLK;

    if (t < ABLK) sOff[t] = row_start[nodeBase + t];
    if (t == ABLK) {
        int last = nodeBase + ABLK - 1;   // block always inside one bucket (128 | 256)
        sOff[ABLK] = row_start[last] + deg[last];
    }
    __syncthreads();

    // phase A: stage this block's edge indices (cnt <= CAP/2 margin <= BUFSZ)
    int* sEdge = (int*)sBuf;
    const int e_begin = sOff[0];
    const int cnt = sOff[ABLK] - e_begin;
    for (int j = t; j < cnt; j += 1024) sEdge[j] = ebuf[e_begin + j];
    __syncthreads();

    const int lane = t & 63;
    const int r = (t >> 6) * 8 + (lane >> 3);   // dst row 0..127, one per 8-lane group
    const int q = lane & 7;
    const int i = nodeBase + r;
    const uint2* yh2 = (const uint2*)y_h;       // row i: yh2[i*8 + q] = 4 halves

    if (i < N_AGENT) {
        int e0 = sOff[r] - e_begin, e1 = sOff[r + 1] - e_begin;
        float ax = 0.f, ay = 0.f, az = 0.f, aw = 0.f;
        for (int j = e0; j < e1; j += 8) {
            uint2 v[8];
#pragma unroll
            for (int u = 0; u < 8; ++u) {
                int idx = (j + u < e1) ? sEdge[j + u] : N_NODES;
                v[u] = yh2[(size_t)idx * 8 + q];
            }
#pragma unroll
            for (int u = 0; u < 8; ++u) {
                __half2 h0 = *reinterpret_cast<__half2*>(&v[u].x);
                __half2 h1 = *reinterpret_cast<__half2*>(&v[u].y);
                float2 f0 = __half22float2(h0);
                float2 f1 = __half22float2(h1);
                ax += f0.x; ay += f0.y; az += f1.x; aw += f1.y;
            }
        }
        *(float4*)&sAcc[r * 32 + q * 4] = make_float4(ax, ay, az, aw);
    }
    __syncthreads();

    // phase B: overwrite sBuf with epilogue weights (L2-hot, ~11 loads/thread)
    sBuf[OF_MZ + t] = Mz[t];
    sBuf[OF_MH + t] = Mh[t];
    for (int j = t; j < 2048; j += 1024) sBuf[OF_W1 + j] = W1[j];
    for (int j = t; j < 6400; j += 1024) sBuf[OF_W2 + j] = W2[j];
    if (t < 32) { sBuf[OF_BZ + t] = bz_eff[t]; sBuf[OF_BH + t] = bh_eff[t]; }
    if (t >= 64 && t < 128) sBuf[OF_B1 + t - 64] = b1[t - 64];
    if (t >= 128 && t < 228) sBuf[OF_B2 + t - 128] = b2[t - 128];
    __syncthreads();

    // epilogue: 32 groups of 32 lanes, 4 rows each
    const float s = *s_ptr;
    const int c = t & 31, g2 = t >> 5;
    for (int rr = g2; rr < ABLK; rr += 32) {
        int ii = nodeBase + rr;
        if (ii >= N_AGENT) break;
        float di = rsqrtf((float)deg[ii] + 1.0f);
        float selfv = __half2float(y_h[(size_t)ii * HID + c]);
        float a = (sAcc[rr * 32 + c] + selfv) * di;
        float uz = sBuf[OF_BZ + c], uh = sBuf[OF_BH + c];
#pragma unroll
        for (int k = 0; k < 32; ++k) {
            float ak = __shfl(a, k, 32);
            uz += ak * sBuf[OF_MZ + k * 32 + c];
            uh += ak * sBuf[OF_MH + k * 32 + c];
        }
        float z = 1.0f / (1.0f + expf(-uz));
        float h = s * (1.0f - z) * tanhf(uh);
        h = fmaxf(h, 0.0f);
        float t0 = sBuf[OF_B1 + c], t1 = sBuf[OF_B1 + c + 32];
#pragma unroll
        for (int k = 0; k < 32; ++k) {
            float hk = __shfl(h, k, 32);
            t0 += hk * sBuf[OF_W1 + k * 64 + c];
            t1 += hk * sBuf[OF_W1 + k * 64 + c + 32];
        }
        t0 = fmaxf(t0, 0.0f); t1 = fmaxf(t1, 0.0f);
        int j3 = (c < 4) ? (c + 96) : 99;
        float o0 = sBuf[OF_B2 + c];
        float o1 = sBuf[OF_B2 + c + 32];
        float o2 = sBuf[OF_B2 + c + 64];
        float o3 = sBuf[OF_B2 + j3];
#pragma unroll
        for (int k = 0; k < 32; ++k) {
            float ta = __shfl(t0, k, 32);
            float tb = __shfl(t1, k, 32);
            o0 += ta * sBuf[OF_W2 + k * 100 + c]      + tb * sBuf[OF_W2 + (k + 32) * 100 + c];
            o1 += ta * sBuf[OF_W2 + k * 100 + c + 32] + tb * sBuf[OF_W2 + (k + 32) * 100 + c + 32];
            o2 += ta * sBuf[OF_W2 + k * 100 + c + 64] + tb * sBuf[OF_W2 + (k + 32) * 100 + c + 64];
            o3 += ta * sBuf[OF_W2 + k * 100 + j3]     + tb * sBuf[OF_W2 + (k + 32) * 100 + j3];
        }
        float* orow = out + (size_t)ii * 100;
        orow[c] = o0;
        orow[c + 32] = o1;
        orow[c + 64] = o2;
        if (c < 4) orow[c + 96] = o3;
    }
}

extern "C" void kernel_launch(void* const* d_in, const int* in_sizes, int n_in,
                              void* d_out, int out_size, void* d_ws, size_t ws_size,
                              hipStream_t stream) {
    const float* agent_x = (const float*)d_in[0];
    const float* map_x   = (const float*)d_in[1];
    const int*   ei      = (const int*)d_in[2];
    const float* W_agent = (const float*)d_in[3];
    const float* b_agent = (const float*)d_in[4];
    const float* W_map   = (const float*)d_in[5];
    const float* b_map   = (const float*)d_in[6];
    const float* Wz_c    = (const float*)d_in[7];
    const float* bz_c    = (const float*)d_in[8];
    const float* Wh_c    = (const float*)d_in[11];
    const float* bh_c    = (const float*)d_in[12];
    const float* Wz_l    = (const float*)d_in[13];
    const float* bz_l    = (const float*)d_in[14];
    const float* Wh_l    = (const float*)d_in[17];
    const float* bh_l    = (const float*)d_in[18];
    const float* attn    = (const float*)d_in[19];
    const float* W1      = (const float*)d_in[20];
    const float* b1      = (const float*)d_in[21];
    const float* W2      = (const float*)d_in[22];
    const float* b2      = (const float*)d_in[23];
    float* out = (float*)d_out;

    const int* e_src = ei;
    const int* e_dst = ei + NE;

    // workspace layout (float-element offsets); total ~23.1 MB
    float*  ws       = (float*)d_ws;
    __half* y_h      = (__half*)ws;                 // (N_NODES+1)*32 halves -> 1,600,128 floats
    float*  Mz       = ws + 1600128;                // 1024
    float*  Mh       = ws + 1601152;                // 1024
    float*  bz       = ws + 1602176;                // 32
    float*  bh       = ws + 1602208;                // 32
    float*  sS       = ws + 1602240;                // 1 (pad to 1602304)
    int*    deg      = (int*)(ws + 1602304);        // 100,000 (pad to 1702400)
    int*    cursor   = (int*)(ws + 1702400);        // 391 (pad to 1702912)
    int*    row_start= (int*)(ws + 1702912);        // 60,160 (pad to 1763328)
    int*    ebuf     = (int*)(ws + 1763328);        // NBUCK*CAP = 4,003,840 -> end 5,767,168

    k_precompute<<<1, 1024, 0, stream>>>(Wz_c, bz_c, Wh_c, bh_c, Wz_l, bz_l,
                                         Wh_l, bh_l, attn, Mz, Mh, bz, bh, sS, cursor);
    k_partition<<<(NE + TILE - 1) / TILE, PTHREADS, 0, stream>>>(e_src, e_dst, cursor, ebuf);
    k_hist<<<NBUCK, 256, 0, stream>>>(cursor, ebuf, deg);
    k_encode<<<((N_NODES + 1) * HID + 255) / 256, 256, 0, stream>>>(
        agent_x, map_x, W_agent, b_agent, W_map, b_map, deg, y_h);
    k_sortlocal<<<NABUCK, 1024, 0, stream>>>(cursor, ebuf, deg, row_start);
    k_aggmlp<<<(N_AGENT + ABLK - 1) / ABLK, 1024, 0, stream>>>(
        row_start, deg, ebuf, y_h, Mz, Mh, bz, bh, sS, W1, b1, W2, b2, out);
}